// Round 4
// baseline (15433.012 us; speedup 1.0000x reference)
//
#include <hip/hip_runtime.h>
#include <math.h>

// ---------------- problem constants ----------------
constexpr int Bc = 2, Sc = 2048, Dc = 1024, Hc = 16, DHc = 64, Rc = 32;
constexpr int Nt = Bc * Sc;  // 4096 tokens
constexpr int NP3 = 1536;    // batched qkv rank width

typedef __attribute__((ext_vector_type(8))) short bf16x8;
typedef __attribute__((ext_vector_type(4))) float f32x4;

// ---------------- bf16 helpers (raw ushort storage) ----------------
__device__ __forceinline__ unsigned short f2bf(float f) {
  unsigned u = __float_as_uint(f);
  u += 0x7fffu + ((u >> 16) & 1u);  // RNE
  return (unsigned short)(u >> 16);
}
__device__ __forceinline__ float bf2f(unsigned short h) {
  return __uint_as_float(((unsigned)h) << 16);
}
// unpack 8 bf16 (in a uint4) -> 8 floats
__device__ __forceinline__ void bf8_to_f(uint4 u, float* f) {
  f[0] = __uint_as_float(u.x << 16); f[1] = __uint_as_float(u.x & 0xffff0000u);
  f[2] = __uint_as_float(u.y << 16); f[3] = __uint_as_float(u.y & 0xffff0000u);
  f[4] = __uint_as_float(u.z << 16); f[5] = __uint_as_float(u.z & 0xffff0000u);
  f[6] = __uint_as_float(u.w << 16); f[7] = __uint_as_float(u.w & 0xffff0000u);
}

#define GLOAD_LDS16(gp, lp)                                                    \
  __builtin_amdgcn_global_load_lds(                                            \
      (const __attribute__((address_space(1))) void*)(gp),                     \
      (__attribute__((address_space(3))) void*)(lp), 16, 0, 0)

// ---------------- LayerNorm (f32 in, bf16 out) ----------------
__global__ __launch_bounds__(256) void ln_kernel(
    const float* __restrict__ X, const float* __restrict__ w,
    const float* __restrict__ b, unsigned short* __restrict__ Out) {
  int row = blockIdx.x;
  const float* x = X + (size_t)row * Dc;
  unsigned short* o = Out + (size_t)row * Dc;
  int tid = threadIdx.x;
  float4 v = ((const float4*)x)[tid];
  float s  = v.x + v.y + v.z + v.w;
  float sq = v.x * v.x + v.y * v.y + v.z * v.z + v.w * v.w;
#pragma unroll
  for (int off = 32; off; off >>= 1) {
    s  += __shfl_down(s, off);
    sq += __shfl_down(sq, off);
  }
  __shared__ float rs[4], rq[4];
  int wid = tid >> 6, lane = tid & 63;
  if (lane == 0) { rs[wid] = s; rq[wid] = sq; }
  __syncthreads();
  float ts = rs[0] + rs[1] + rs[2] + rs[3];
  float tq = rq[0] + rq[1] + rq[2] + rq[3];
  float mean = ts * (1.f / Dc);
  float var  = tq * (1.f / Dc) - mean * mean;
  float rstd = rsqrtf(var + 1e-5f);
  float4 wv = ((const float4*)w)[tid];
  float4 bv = ((const float4*)b)[tid];
  ushort4 ov;
  ov.x = f2bf((v.x - mean) * rstd * wv.x + bv.x);
  ov.y = f2bf((v.y - mean) * rstd * wv.y + bv.y);
  ov.z = f2bf((v.z - mean) * rstd * wv.z + bv.z);
  ov.w = f2bf((v.w - mean) * rstd * wv.w + bv.w);
  ((ushort4*)o)[tid] = ov;
}

// ---------------- transpose + cvt: in R x C f32 -> out C x R bf16 ----------
__global__ __launch_bounds__(256) void transpose_cvt(
    const float* __restrict__ in, unsigned short* __restrict__ out,
    int R, int C) {
  __shared__ float t[32][33];
  int tx = threadIdx.x & 31, ty = threadIdx.x >> 5;  // ty 0..7
  int r0 = blockIdx.y * 32, c0 = blockIdx.x * 32;
#pragma unroll
  for (int i = 0; i < 4; ++i)
    t[ty + i * 8][tx] = in[(size_t)(r0 + ty + i * 8) * C + c0 + tx];
  __syncthreads();
#pragma unroll
  for (int i = 0; i < 4; ++i)
    out[(size_t)(c0 + ty + i * 8) * R + r0 + tx] = f2bf(t[tx][ty + i * 8]);
}

// ---------------- bf16 MFMA GEMM (m97 structure) ----------------
// C(MxN) = epi(A(MxK) @ BT(NxK)^T). A,BT bf16 row-major. 128x128 tile, BK=32,
// 256 thr = 4 waves (2x2), each wave 64x64 via 4x4 mfma_f32_16x16x32_bf16.
__device__ __forceinline__ float gelu_f(float v) {
  float c = v + 0.044715f * v * v * v;
  return 0.5f * v * (1.f + tanhf(0.7978845608028654f * c));
}

template <bool OBF16, int ACT, bool BIAS, bool RES>
__global__ __launch_bounds__(256) void gemm_bf(
    const unsigned short* __restrict__ A, const unsigned short* __restrict__ BT,
    const float* __restrict__ bias, const float* __restrict__ res,
    void* __restrict__ Cv, int M, int N, int K) {
  __shared__ unsigned short As[128 * 32];
  __shared__ unsigned short Bs[128 * 32];
  int tid = threadIdx.x;
  int lane = tid & 63, wv = tid >> 6;
  int bm = blockIdx.y * 128, bn = blockIdx.x * 128;
  int wr = wv >> 1, wc = wv & 1;
  f32x4 acc[4][4] = {};
  // staging: per call, wave base = c*2048 + wv*512 elems; lane covers +lane*8
  int soff0 = wv * 512 + lane * 8;
  int soff1 = soff0 + 2048;
  int ar0 = soff0 >> 5, ak0 = soff0 & 31;
  int ar1 = soff1 >> 5, ak1 = soff1 & 31;
  const unsigned short* Ab = A + (size_t)bm * K;
  const unsigned short* Bb = BT + (size_t)bn * K;
  for (int k0 = 0; k0 < K; k0 += 32) {
    __syncthreads();
    GLOAD_LDS16(Ab + (size_t)ar0 * K + k0 + ak0, As + wv * 512);
    GLOAD_LDS16(Ab + (size_t)ar1 * K + k0 + ak1, As + 2048 + wv * 512);
    GLOAD_LDS16(Bb + (size_t)ar0 * K + k0 + ak0, Bs + wv * 512);
    GLOAD_LDS16(Bb + (size_t)ar1 * K + k0 + ak1, Bs + 2048 + wv * 512);
    __syncthreads();
    bf16x8 af[4], bf[4];
#pragma unroll
    for (int m = 0; m < 4; ++m)
      af[m] = *(const bf16x8*)&As[(wr * 64 + m * 16 + (lane & 15)) * 32 + (lane >> 4) * 8];
#pragma unroll
    for (int n = 0; n < 4; ++n)
      bf[n] = *(const bf16x8*)&Bs[(wc * 64 + n * 16 + (lane & 15)) * 32 + (lane >> 4) * 8];
#pragma unroll
    for (int m = 0; m < 4; ++m)
#pragma unroll
      for (int n = 0; n < 4; ++n)
        acc[m][n] = __builtin_amdgcn_mfma_f32_16x16x32_bf16(af[m], bf[n], acc[m][n], 0, 0, 0);
  }
  int cg = lane >> 4;  // row group
#pragma unroll
  for (int m = 0; m < 4; ++m) {
#pragma unroll
    for (int n = 0; n < 4; ++n) {
      int row0 = bm + wr * 64 + m * 16 + cg * 4;
      int col  = bn + wc * 64 + n * 16 + (lane & 15);
      float bb = BIAS ? bias[col] : 0.f;
#pragma unroll
      for (int i = 0; i < 4; ++i) {
        float v = acc[m][n][i];
        if (BIAS) v += bb;
        if (ACT == 1) v = gelu_f(v);
        if (RES) v += res[(size_t)(row0 + i) * N + col];
        if (OBF16)
          ((unsigned short*)Cv)[(size_t)(row0 + i) * N + col] = f2bf(v);
        else
          ((float*)Cv)[(size_t)(row0 + i) * N + col] = v;
      }
    }
  }
}

// ---------------- per-head rank->head projection ----------------
// Out[b,h,s,e] = sum_r P[n, colOff + h*32 + r] * Vw[h,r,e] + bias[h,e]
// P bf16 (Nt x 1536), Vw f32, Out bf16 (B,H,S,DH)
__global__ __launch_bounds__(256) void pv_kernel(
    const unsigned short* __restrict__ P, const float* __restrict__ Vw,
    const float* __restrict__ bias, unsigned short* __restrict__ Out,
    int colOff) {
  int idx = blockIdx.x * 256 + threadIdx.x;
  int e = idx & 63;
  int h = (idx >> 6) & 15;
  int n = idx >> 10;
  const unsigned short* prow = P + (size_t)n * NP3 + colOff + h * Rc;
  const float* vcol = Vw + h * (Rc * DHc) + e;
  float acc = 0.f;
#pragma unroll
  for (int r = 0; r < Rc; ++r) acc = fmaf(bf2f(prow[r]), vcol[r * DHc], acc);
  acc += bias[(h << 6) + e];
  int b = n / Sc, s = n % Sc;
  Out[(((size_t)(b * Hc + h) * Sc + s) << 6) + e] = f2bf(acc);
}

// ---------------- causal flash attention (scalar f32, bf16 K/V in LDS) -----
// block = (bh, 64-row q-tile), 256 thr. thread: r = tid>>2 (q row), c4 = tid&3
// owns dims d0 = c4*16 .. +16 (Q and O in regs) and key quarter c4*16..+16.
__global__ __launch_bounds__(256) void attn_kernel(
    const unsigned short* __restrict__ Q, const unsigned short* __restrict__ K,
    const unsigned short* __restrict__ V, unsigned short* __restrict__ Y) {
  __shared__ unsigned short Ks[64 * 64];
  __shared__ unsigned short Vs[64 * 64];
  int bid = blockIdx.x;
  int bh = bid >> 5;
  int qt = 31 - (bid & 31);  // big tiles first
  int qbase = qt * 64;
  const unsigned short* Qg = Q + (size_t)bh * Sc * 64;
  const unsigned short* Kg = K + (size_t)bh * Sc * 64;
  const unsigned short* Vg = V + (size_t)bh * Sc * 64;
  int tid = threadIdx.x;
  int lane = tid & 63, wv = tid >> 6;
  int r = tid >> 2, c4 = tid & 3, d0 = c4 * 16;
  // load Q row segment, fold in softmax scale
  float Qr[16];
  {
    const unsigned short* qrow = Qg + (size_t)(qbase + r) * 64 + d0;
    bf8_to_f(*(const uint4*)qrow, Qr);
    bf8_to_f(*(const uint4*)(qrow + 8), Qr + 8);
#pragma unroll
    for (int j = 0; j < 16; ++j) Qr[j] *= 0.125f;
  }
  float O[16] = {};
  float m = -1e30f, l = 0.f;
  int soff = wv * 512 + lane * 8;   // staging elem offset (call 0)
  for (int kt = 0; kt <= qt; ++kt) {
    __syncthreads();
    {  // stage 64x64 K and V tiles (bf16, linear LDS)
      int row0 = soff >> 6, col0 = soff & 63;
      int row1 = (soff + 2048) >> 6, col1 = col0;
      const unsigned short* Kt = Kg + (size_t)(kt * 64) * 64;
      const unsigned short* Vt = Vg + (size_t)(kt * 64) * 64;
      GLOAD_LDS16(Kt + (size_t)row0 * 64 + col0, Ks + soff);
      GLOAD_LDS16(Kt + (size_t)row1 * 64 + col1, Ks + 2048 + soff);
      GLOAD_LDS16(Vt + (size_t)row0 * 64 + col0, Vs + soff);
      GLOAD_LDS16(Vt + (size_t)row1 * 64 + col1, Vs + 2048 + soff);
    }
    __syncthreads();
    // ---- scores: thread computes 16-dim partial for all 64 keys, 4-lane sum
    // FULL unroll: kk compile-time so sk[] stays in VGPRs (rule #20)
    float sk[16];
#pragma unroll
    for (int kk = 0; kk < 64; ++kk) {
      float kf[16];
      bf8_to_f(*(const uint4*)&Ks[kk * 64 + d0], kf);
      bf8_to_f(*(const uint4*)&Ks[kk * 64 + d0 + 8], kf + 8);
      float part = 0.f;
#pragma unroll
      for (int j = 0; j < 16; ++j) part = fmaf(Qr[j], kf[j], part);
      part += __shfl_xor(part, 1);
      part += __shfl_xor(part, 2);
      if ((kk >> 4) == c4) sk[kk & 15] = part;
    }
    // causal mask on diagonal tile
    if (kt == qt) {
#pragma unroll
      for (int jj = 0; jj < 16; ++jj)
        if (d0 + jj > r) sk[jj] = -1e30f;
    }
    // ---- online softmax
    float mloc = sk[0];
#pragma unroll
    for (int jj = 1; jj < 16; ++jj) mloc = fmaxf(mloc, sk[jj]);
    mloc = fmaxf(mloc, __shfl_xor(mloc, 1));
    mloc = fmaxf(mloc, __shfl_xor(mloc, 2));
    float m_new = fmaxf(m, mloc);
    float scale = __expf(m - m_new);
    float pl[16];
    float lloc = 0.f;
#pragma unroll
    for (int jj = 0; jj < 16; ++jj) {
      pl[jj] = __expf(sk[jj] - m_new);
      lloc += pl[jj];
    }
    lloc += __shfl_xor(lloc, 1);
    lloc += __shfl_xor(lloc, 2);
    l = l * scale + lloc;
    m = m_new;
#pragma unroll
    for (int j = 0; j < 16; ++j) O[j] *= scale;
    // ---- PV: O[d0..+16] += sum_k p[k] * V[k][d0..+16]
    // FULL unroll on jj: pl[jj] compile-time indexed (rule #20)
#pragma unroll
    for (int qq = 0; qq < 4; ++qq) {
      int srcl = (lane & ~3) | qq;
#pragma unroll
      for (int jj = 0; jj < 16; ++jj) {
        float pk = __shfl(pl[jj], srcl);
        int kk = qq * 16 + jj;
        float vf[16];
        bf8_to_f(*(const uint4*)&Vs[kk * 64 + d0], vf);
        bf8_to_f(*(const uint4*)&Vs[kk * 64 + d0 + 8], vf + 8);
#pragma unroll
        for (int j = 0; j < 16; ++j) O[j] = fmaf(pk, vf[j], O[j]);
      }
    }
  }
  // ---- write out (B,S,H*DH) bf16
  float inv = 1.f / l;
  unsigned short ob[16];
#pragma unroll
  for (int j = 0; j < 16; ++j) ob[j] = f2bf(O[j] * inv);
  int b = bh >> 4, h = bh & 15;
  unsigned short* yrow = Y + (size_t)(b * Sc + qbase + r) * Dc + h * 64 + d0;
  *(uint4*)yrow = *(const uint4*)ob;
  *(uint4*)(yrow + 8) = *(const uint4*)(ob + 8);
}

// ---------------- launch ----------------
extern "C" void kernel_launch(void* const* d_in, const int* in_sizes, int n_in,
                              void* d_out, int out_size, void* d_ws, size_t ws_size,
                              hipStream_t stream) {
  const float* hidden = (const float*)d_in[0];
  const float* ln1_w = (const float*)d_in[2];
  const float* ln1_b = (const float*)d_in[3];
  const float* q_U = (const float*)d_in[4];
  const float* q_V = (const float*)d_in[5];
  const float* q_b = (const float*)d_in[6];
  const float* k_U = (const float*)d_in[7];
  const float* k_V = (const float*)d_in[8];
  const float* k_b = (const float*)d_in[9];
  const float* v_U = (const float*)d_in[10];
  const float* v_V = (const float*)d_in[11];
  const float* v_b = (const float*)d_in[12];
  const float* out_U = (const float*)d_in[13];
  const float* out_V = (const float*)d_in[14];
  const float* out_b = (const float*)d_in[15];
  const float* ln2_w = (const float*)d_in[16];
  const float* ln2_b = (const float*)d_in[17];
  const float* fc1_U = (const float*)d_in[18];
  const float* fc1_V = (const float*)d_in[19];
  const float* fc1_b = (const float*)d_in[20];
  const float* fc2_U = (const float*)d_in[21];
  const float* fc2_V = (const float*)d_in[22];
  const float* fc2_b = (const float*)d_in[23];
  float* out = (float*)d_out;

  // ---- workspace layout (byte offsets, all 1MB-aligned) ----
  char* wsb = (char*)d_ws;
  auto US = [&](size_t mb) { return (unsigned short*)(wsb + mb * 1024 * 1024); };
  unsigned short* WqkvT = US(0);    // 1536x1024 bf16  (3MB)
  unsigned short* outUT = US(3);    // 512x1024        (1MB)
  unsigned short* outVT = US(4);    // 1024x512        (1MB)
  unsigned short* fc1UT = US(5);    // 512x1024        (1MB)
  unsigned short* fc1VT = US(6);    // 4096x512        (4MB)
  unsigned short* fc2UT = US(10);   // 512x4096        (4MB)
  unsigned short* fc2VT = US(14);   // 1024x512        (1MB)
  unsigned short* xb    = US(15);   // 4096x1024       (8MB)
  unsigned short* Pqkv  = US(23);   // 4096x1536       (12MB)
  unsigned short* Qb    = US(35);   // (B,H,S,DH)      (8MB)
  unsigned short* Kb    = US(43);
  unsigned short* Vb    = US(51);
  unsigned short* Yb    = US(59);   // 4096x1024       (8MB)
  unsigned short* Tb    = US(67);   // 4096x512        (4MB)
  float*          hb    = (float*)(wsb + 71ull * 1024 * 1024);  // 16MB
  unsigned short* ab    = US(87);   // 4096x4096       (32MB) -> ends 119MB

  // ---- 1. weight transposes (f32 -> bf16 N x K) ----
  transpose_cvt<<<dim3(512 / 32, 1024 / 32), 256, 0, stream>>>(q_U, WqkvT, 1024, 512);
  transpose_cvt<<<dim3(512 / 32, 1024 / 32), 256, 0, stream>>>(k_U, WqkvT + 512 * 1024, 1024, 512);
  transpose_cvt<<<dim3(512 / 32, 1024 / 32), 256, 0, stream>>>(v_U, WqkvT + 1024 * 1024, 1024, 512);
  transpose_cvt<<<dim3(512 / 32, 1024 / 32), 256, 0, stream>>>(out_U, outUT, 1024, 512);
  transpose_cvt<<<dim3(1024 / 32, 512 / 32), 256, 0, stream>>>(out_V, outVT, 512, 1024);
  transpose_cvt<<<dim3(512 / 32, 1024 / 32), 256, 0, stream>>>(fc1_U, fc1UT, 1024, 512);
  transpose_cvt<<<dim3(4096 / 32, 512 / 32), 256, 0, stream>>>(fc1_V, fc1VT, 512, 4096);
  transpose_cvt<<<dim3(512 / 32, 4096 / 32), 256, 0, stream>>>(fc2_U, fc2UT, 4096, 512);
  transpose_cvt<<<dim3(1024 / 32, 512 / 32), 256, 0, stream>>>(fc2_V, fc2VT, 512, 1024);

  // ---- 2. LN1 -> xb (bf16) ----
  ln_kernel<<<Nt, 256, 0, stream>>>(hidden, ln1_w, ln1_b, xb);
  // ---- 3. batched QKV rank projection: xb @ [qU kU vU] -> Pqkv ----
  gemm_bf<true, 0, false, false><<<dim3(NP3 / 128, Nt / 128), 256, 0, stream>>>(
      xb, WqkvT, nullptr, nullptr, Pqkv, Nt, NP3, Dc);
  // ---- 4. per-head R->DH (+bias) -> Q,K,V (B,H,S,DH) bf16 ----
  int pvBlocks = Nt * Hc * DHc / 256;
  pv_kernel<<<pvBlocks, 256, 0, stream>>>(Pqkv, q_V, q_b, Qb, 0);
  pv_kernel<<<pvBlocks, 256, 0, stream>>>(Pqkv, k_V, k_b, Kb, 512);
  pv_kernel<<<pvBlocks, 256, 0, stream>>>(Pqkv, v_V, v_b, Vb, 1024);
  // ---- 5. attention -> Yb (B,S,D) bf16 ----
  attn_kernel<<<Bc * Hc * (Sc / 64), 256, 0, stream>>>(Qb, Kb, Vb, Yb);
  // ---- 6. out-proj ----
  gemm_bf<true, 0, false, false><<<dim3(512 / 128, Nt / 128), 256, 0, stream>>>(
      Yb, outUT, nullptr, nullptr, Tb, Nt, 512, Dc);
  gemm_bf<false, 0, true, true><<<dim3(Dc / 128, Nt / 128), 256, 0, stream>>>(
      Tb, outVT, out_b, hidden, hb, Nt, Dc, 512);
  // ---- 7. LN2 -> xb (bf16) ----
  ln_kernel<<<Nt, 256, 0, stream>>>(hb, ln2_w, ln2_b, xb);
  // ---- 8. MLP ----
  gemm_bf<true, 0, false, false><<<dim3(512 / 128, Nt / 128), 256, 0, stream>>>(
      xb, fc1UT, nullptr, nullptr, Tb, Nt, 512, Dc);
  gemm_bf<true, 1, true, false><<<dim3(4096 / 128, Nt / 128), 256, 0, stream>>>(
      Tb, fc1VT, fc1_b, nullptr, ab, Nt, 4096, 512);
  gemm_bf<true, 0, false, false><<<dim3(512 / 128, Nt / 128), 256, 0, stream>>>(
      ab, fc2UT, nullptr, nullptr, Tb, Nt, 512, 4096);
  gemm_bf<false, 0, true, true><<<dim3(Dc / 128, Nt / 128), 256, 0, stream>>>(
      Tb, fc2VT, fc2_b, hb, out, Nt, Dc, 512);
}

// Round 9
// 597.015 us; speedup vs baseline: 25.8503x; 25.8503x over previous
//
#include <hip/hip_runtime.h>
#include <math.h>

// ---------------- problem constants ----------------
constexpr int Bc = 2, Sc = 2048, Dc = 1024, Hc = 16, DHc = 64, Rc = 32;
constexpr int Nt = Bc * Sc;  // 4096 tokens
constexpr int NP3 = 1536;    // batched qkv rank width

typedef __attribute__((ext_vector_type(8))) short bf16x8;
typedef __attribute__((ext_vector_type(4))) float f32x4;

// ---------------- bf16 helpers (raw ushort storage) ----------------
__device__ __forceinline__ unsigned short f2bf(float f) {
  unsigned u = __float_as_uint(f);
  u += 0x7fffu + ((u >> 16) & 1u);  // RNE
  return (unsigned short)(u >> 16);
}
__device__ __forceinline__ float bf2f(unsigned short h) {
  return __uint_as_float(((unsigned)h) << 16);
}

#define GLOAD_LDS16(gp, lp)                                                    \
  __builtin_amdgcn_global_load_lds(                                            \
      (const __attribute__((address_space(1))) void*)(gp),                     \
      (__attribute__((address_space(3))) void*)(lp), 16, 0, 0)

// ---------------- LayerNorm (f32 in, bf16 out) ----------------
__global__ __launch_bounds__(256) void ln_kernel(
    const float* __restrict__ X, const float* __restrict__ w,
    const float* __restrict__ b, unsigned short* __restrict__ Out) {
  int row = blockIdx.x;
  const float* x = X + (size_t)row * Dc;
  unsigned short* o = Out + (size_t)row * Dc;
  int tid = threadIdx.x;
  float4 v = ((const float4*)x)[tid];
  float s  = v.x + v.y + v.z + v.w;
  float sq = v.x * v.x + v.y * v.y + v.z * v.z + v.w * v.w;
#pragma unroll
  for (int off = 32; off; off >>= 1) {
    s  += __shfl_down(s, off);
    sq += __shfl_down(sq, off);
  }
  __shared__ float rs[4], rq[4];
  int wid = tid >> 6, lane = tid & 63;
  if (lane == 0) { rs[wid] = s; rq[wid] = sq; }
  __syncthreads();
  float ts = rs[0] + rs[1] + rs[2] + rs[3];
  float tq = rq[0] + rq[1] + rq[2] + rq[3];
  float mean = ts * (1.f / Dc);
  float var  = tq * (1.f / Dc) - mean * mean;
  float rstd = rsqrtf(var + 1e-5f);
  float4 wv = ((const float4*)w)[tid];
  float4 bv = ((const float4*)b)[tid];
  ushort4 ov;
  ov.x = f2bf((v.x - mean) * rstd * wv.x + bv.x);
  ov.y = f2bf((v.y - mean) * rstd * wv.y + bv.y);
  ov.z = f2bf((v.z - mean) * rstd * wv.z + bv.z);
  ov.w = f2bf((v.w - mean) * rstd * wv.w + bv.w);
  ((ushort4*)o)[tid] = ov;
}

// ---------------- transpose + cvt: in R x C f32 -> out C x R bf16 ----------
__global__ __launch_bounds__(256) void transpose_cvt(
    const float* __restrict__ in, unsigned short* __restrict__ out,
    int R, int C) {
  __shared__ float t[32][33];
  int tx = threadIdx.x & 31, ty = threadIdx.x >> 5;  // ty 0..7
  int r0 = blockIdx.y * 32, c0 = blockIdx.x * 32;
#pragma unroll
  for (int i = 0; i < 4; ++i)
    t[ty + i * 8][tx] = in[(size_t)(r0 + ty + i * 8) * C + c0 + tx];
  __syncthreads();
#pragma unroll
  for (int i = 0; i < 4; ++i)
    out[(size_t)(c0 + ty + i * 8) * R + r0 + tx] = f2bf(t[tx][ty + i * 8]);
}

// ---------------- bf16 transpose (B,H,S,DH) -> (B,H,DH,S) ----------------
__global__ __launch_bounds__(256) void transpose_hd(
    const unsigned short* __restrict__ in, unsigned short* __restrict__ out) {
  __shared__ unsigned short t[32][33];
  int bh = blockIdx.z;
  int s0 = blockIdx.x * 32, e0 = blockIdx.y * 32;
  int tx = threadIdx.x & 31, ty = threadIdx.x >> 5;
  const unsigned short* ib = in + ((size_t)bh * Sc + s0) * 64 + e0;
  unsigned short* ob = out + ((size_t)bh * 64 + e0) * Sc + s0;
#pragma unroll
  for (int i = 0; i < 4; ++i)
    t[ty + i * 8][tx] = ib[(size_t)(ty + i * 8) * 64 + tx];
  __syncthreads();
#pragma unroll
  for (int i = 0; i < 4; ++i)
    ob[(size_t)(ty + i * 8) * Sc + tx] = t[tx][ty + i * 8];
}

// ---------------- bf16 MFMA GEMM (m97 structure) ----------------
__device__ __forceinline__ float gelu_f(float v) {
  float c = v + 0.044715f * v * v * v;
  return 0.5f * v * (1.f + tanhf(0.7978845608028654f * c));
}

template <bool OBF16, int ACT, bool BIAS, bool RES>
__global__ __launch_bounds__(256) void gemm_bf(
    const unsigned short* __restrict__ A, const unsigned short* __restrict__ BT,
    const float* __restrict__ bias, const float* __restrict__ res,
    void* __restrict__ Cv, int M, int N, int K) {
  __shared__ unsigned short As[128 * 32];
  __shared__ unsigned short Bs[128 * 32];
  int tid = threadIdx.x;
  int lane = tid & 63, wv = tid >> 6;
  int bm = blockIdx.y * 128, bn = blockIdx.x * 128;
  int wr = wv >> 1, wc = wv & 1;
  f32x4 acc[4][4] = {};
  int soff0 = wv * 512 + lane * 8;
  int soff1 = soff0 + 2048;
  int ar0 = soff0 >> 5, ak0 = soff0 & 31;
  int ar1 = soff1 >> 5, ak1 = soff1 & 31;
  const unsigned short* Ab = A + (size_t)bm * K;
  const unsigned short* Bb = BT + (size_t)bn * K;
  for (int k0 = 0; k0 < K; k0 += 32) {
    __syncthreads();
    GLOAD_LDS16(Ab + (size_t)ar0 * K + k0 + ak0, As + wv * 512);
    GLOAD_LDS16(Ab + (size_t)ar1 * K + k0 + ak1, As + 2048 + wv * 512);
    GLOAD_LDS16(Bb + (size_t)ar0 * K + k0 + ak0, Bs + wv * 512);
    GLOAD_LDS16(Bb + (size_t)ar1 * K + k0 + ak1, Bs + 2048 + wv * 512);
    __syncthreads();
    bf16x8 af[4], bf[4];
#pragma unroll
    for (int m = 0; m < 4; ++m)
      af[m] = *(const bf16x8*)&As[(wr * 64 + m * 16 + (lane & 15)) * 32 + (lane >> 4) * 8];
#pragma unroll
    for (int n = 0; n < 4; ++n)
      bf[n] = *(const bf16x8*)&Bs[(wc * 64 + n * 16 + (lane & 15)) * 32 + (lane >> 4) * 8];
#pragma unroll
    for (int m = 0; m < 4; ++m)
#pragma unroll
      for (int n = 0; n < 4; ++n)
        acc[m][n] = __builtin_amdgcn_mfma_f32_16x16x32_bf16(af[m], bf[n], acc[m][n], 0, 0, 0);
  }
  int cg = lane >> 4;
#pragma unroll
  for (int m = 0; m < 4; ++m) {
#pragma unroll
    for (int n = 0; n < 4; ++n) {
      int row0 = bm + wr * 64 + m * 16 + cg * 4;
      int col  = bn + wc * 64 + n * 16 + (lane & 15);
      float bb = BIAS ? bias[col] : 0.f;
#pragma unroll
      for (int i = 0; i < 4; ++i) {
        float v = acc[m][n][i];
        if (BIAS) v += bb;
        if (ACT == 1) v = gelu_f(v);
        if (RES) v += res[(size_t)(row0 + i) * N + col];
        if (OBF16)
          ((unsigned short*)Cv)[(size_t)(row0 + i) * N + col] = f2bf(v);
        else
          ((float*)Cv)[(size_t)(row0 + i) * N + col] = v;
      }
    }
  }
}

// ---------------- per-head rank->head projection ----------------
__global__ __launch_bounds__(256) void pv_kernel(
    const unsigned short* __restrict__ P, const float* __restrict__ Vw,
    const float* __restrict__ bias, unsigned short* __restrict__ Out,
    int colOff) {
  int idx = blockIdx.x * 256 + threadIdx.x;
  int e = idx & 63;
  int h = (idx >> 6) & 15;
  int n = idx >> 10;
  const unsigned short* prow = P + (size_t)n * NP3 + colOff + h * Rc;
  const float* vcol = Vw + h * (Rc * DHc) + e;
  float acc = 0.f;
#pragma unroll
  for (int r = 0; r < Rc; ++r) acc = fmaf(bf2f(prow[r]), vcol[r * DHc], acc);
  acc += bias[(h << 6) + e];
  int b = n / Sc, s = n % Sc;
  Out[(((size_t)(b * Hc + h) * Sc + s) << 6) + e] = f2bf(acc);
}

// ---------------- causal flash attention (MFMA 16x16x32 bf16) ----------------
// block = (bh, 64-row q-tile), 4 waves; wave w owns q rows [qbase+w*16, +16).
// K staged row-major [key][d], V staged TRANSPOSED [d][key]; both XOR-swizzled
// (16B slot index ^= row&7) via pre-swizzled global_load_lds source (m173).
// P re-layout C->A fragment via per-wave swizzled LDS tile.
__global__ __launch_bounds__(256) void attn_kernel(
    const unsigned short* __restrict__ Q, const unsigned short* __restrict__ K,
    const unsigned short* __restrict__ VT, unsigned short* __restrict__ Y) {
  __shared__ unsigned short Ks[64 * 64];
  __shared__ unsigned short Vs[64 * 64];
  __shared__ unsigned short Ps[4][16 * 64];
  int bid = blockIdx.x;
  int bh = bid >> 5;
  int qt = 31 - (bid & 31);  // big tiles first
  int qbase = qt * 64;
  int tid = threadIdx.x, lane = tid & 63, w = tid >> 6;
  int g = lane >> 4, c = lane & 15;
  const unsigned short* Qg = Q + (size_t)bh * Sc * 64;
  const unsigned short* Kg = K + (size_t)bh * Sc * 64;
  const unsigned short* Vg = VT + (size_t)bh * 64 * Sc;
  // Q fragments (A-layout: row=c, k=g*8+j), d-halves 0 / 32
  int q0 = qbase + w * 16;
  bf16x8 qa0 = *(const bf16x8*)(Qg + (size_t)(q0 + c) * 64 + g * 8);
  bf16x8 qa1 = *(const bf16x8*)(Qg + (size_t)(q0 + c) * 64 + 32 + g * 8);
  f32x4 O0 = {0.f, 0.f, 0.f, 0.f}, O1 = O0, O2 = O0, O3 = O0;
  float m[4] = {-1e30f, -1e30f, -1e30f, -1e30f};
  float l[4] = {0.f, 0.f, 0.f, 0.f};
  // staging source precompute: LDS linear slot (r, sl) holds key-block sl^(r&7)
  int r0s = tid >> 3;               // rows 0..31 (call 0)
  int b0s = (tid & 7) ^ (r0s & 7);  // source 16B block
  int r1s = (256 + tid) >> 3;       // rows 32..63 (call 1)
  int b1s = (tid & 7) ^ (r1s & 7);
  size_t kOff0 = (size_t)r0s * 64 + b0s * 8;
  size_t kOff1 = (size_t)r1s * 64 + b1s * 8;
  size_t vOff0 = (size_t)r0s * Sc + b0s * 8;
  size_t vOff1 = (size_t)r1s * Sc + b1s * 8;
  unsigned short* KsD0 = Ks + w * 512;         // wave-uniform dests
  unsigned short* KsD1 = Ks + 2048 + w * 512;
  unsigned short* VsD0 = Vs + w * 512;
  unsigned short* VsD1 = Vs + 2048 + w * 512;
  unsigned short* Pw = Ps[w];
  const f32x4 zero = {0.f, 0.f, 0.f, 0.f};
  int swc = c & 7;

  for (int kt = 0; kt <= qt; ++kt) {
    __syncthreads();
    {
      const unsigned short* Kt = Kg + (size_t)kt * 64 * 64;
      const unsigned short* Vt = Vg + (size_t)kt * 64;
      GLOAD_LDS16(Kt + kOff0, KsD0);
      GLOAD_LDS16(Kt + kOff1, KsD1);
      GLOAD_LDS16(Vt + vOff0, VsD0);
      GLOAD_LDS16(Vt + vOff1, VsD1);
    }
    __syncthreads();
    // ---- scores: S[q=4g+i][key=kb*16+c] via 2 MFMA per key-block
    f32x4 sA[4];
#pragma unroll
    for (int kb = 0; kb < 4; ++kb) {
      int keyr = kb * 16 + c;
      int sw = keyr & 7;
      bf16x8 k0 = *(const bf16x8*)&Ks[keyr * 64 + ((g ^ sw) << 3)];
      bf16x8 k1 = *(const bf16x8*)&Ks[keyr * 64 + (((4 + g) ^ sw) << 3)];
      f32x4 a = __builtin_amdgcn_mfma_f32_16x16x32_bf16(qa0, k0, zero, 0, 0, 0);
      a = __builtin_amdgcn_mfma_f32_16x16x32_bf16(qa1, k1, a, 0, 0, 0);
      sA[kb] = a;
    }
    // ---- scale + causal mask + online softmax (rows spread over 16-lane grp)
    float p[4][4], rm[4];
#pragma unroll
    for (int i = 0; i < 4; ++i) rm[i] = -1e30f;
#pragma unroll
    for (int kb = 0; kb < 4; ++kb)
#pragma unroll
      for (int i = 0; i < 4; ++i) {
        float s = sA[kb][i] * 0.125f;
        if (kt == qt && (kb * 16 + c) > (w * 16 + 4 * g + i)) s = -1e30f;
        p[kb][i] = s;
        rm[i] = fmaxf(rm[i], s);
      }
#pragma unroll
    for (int i = 0; i < 4; ++i) {
      rm[i] = fmaxf(rm[i], __shfl_xor(rm[i], 1));
      rm[i] = fmaxf(rm[i], __shfl_xor(rm[i], 2));
      rm[i] = fmaxf(rm[i], __shfl_xor(rm[i], 4));
      rm[i] = fmaxf(rm[i], __shfl_xor(rm[i], 8));
    }
    float sc[4], ls[4];
#pragma unroll
    for (int i = 0; i < 4; ++i) {
      float mn = fmaxf(m[i], rm[i]);
      sc[i] = __expf(m[i] - mn);
      m[i] = mn;
      ls[i] = 0.f;
    }
#pragma unroll
    for (int kb = 0; kb < 4; ++kb)
#pragma unroll
      for (int i = 0; i < 4; ++i) {
        float e = __expf(p[kb][i] - m[i]);
        p[kb][i] = e;
        ls[i] += e;
      }
#pragma unroll
    for (int i = 0; i < 4; ++i) {
      ls[i] += __shfl_xor(ls[i], 1);
      ls[i] += __shfl_xor(ls[i], 2);
      ls[i] += __shfl_xor(ls[i], 4);
      ls[i] += __shfl_xor(ls[i], 8);
      l[i] = l[i] * sc[i] + ls[i];
      O0[i] *= sc[i]; O1[i] *= sc[i]; O2[i] *= sc[i]; O3[i] *= sc[i];
    }
    // ---- P -> wave-private swizzled LDS tile (bf16)
#pragma unroll
    for (int kb = 0; kb < 4; ++kb)
#pragma unroll
      for (int i = 0; i < 4; ++i) {
        int row = 4 * g + i;
        int slot = (kb * 2 + (c >> 3)) ^ (row & 7);
        Pw[row * 64 + slot * 8 + (c & 7)] = f2bf(p[kb][i]);
      }
    // ---- PV: O[q][d] += P(16x64) @ V(64x64) ; A-frag from Pw, B-frag from Vs
    bf16x8 pa0 = *(const bf16x8*)&Pw[c * 64 + ((g ^ swc) << 3)];
    bf16x8 pa1 = *(const bf16x8*)&Pw[c * 64 + (((4 + g) ^ swc) << 3)];
#define PV_DB(db, Ov)                                                          \
    {                                                                          \
      int d_ = db * 16 + c;                                                    \
      bf16x8 v0 = *(const bf16x8*)&Vs[d_ * 64 + ((g ^ swc) << 3)];             \
      bf16x8 v1 = *(const bf16x8*)&Vs[d_ * 64 + (((4 + g) ^ swc) << 3)];       \
      Ov = __builtin_amdgcn_mfma_f32_16x16x32_bf16(pa0, v0, Ov, 0, 0, 0);      \
      Ov = __builtin_amdgcn_mfma_f32_16x16x32_bf16(pa1, v1, Ov, 0, 0, 0);      \
    }
    PV_DB(0, O0) PV_DB(1, O1) PV_DB(2, O2) PV_DB(3, O3)
#undef PV_DB
  }
  // ---- epilogue: Y[(b, q, h*64+d)] = O/l
  float inv[4];
#pragma unroll
  for (int i = 0; i < 4; ++i) inv[i] = 1.f / l[i];
  int b = bh >> 4, h = bh & 15;
#define WR_DB(db, Ov)                                                          \
  {                                                                            \
    _Pragma("unroll")                                                          \
    for (int i = 0; i < 4; ++i) {                                              \
      int q_ = q0 + 4 * g + i;                                                 \
      Y[(size_t)(b * Sc + q_) * Dc + h * 64 + db * 16 + c] =                   \
          f2bf(Ov[i] * inv[i]);                                                \
    }                                                                          \
  }
  WR_DB(0, O0) WR_DB(1, O1) WR_DB(2, O2) WR_DB(3, O3)
#undef WR_DB
}

// ---------------- launch ----------------
extern "C" void kernel_launch(void* const* d_in, const int* in_sizes, int n_in,
                              void* d_out, int out_size, void* d_ws, size_t ws_size,
                              hipStream_t stream) {
  const float* hidden = (const float*)d_in[0];
  const float* ln1_w = (const float*)d_in[2];
  const float* ln1_b = (const float*)d_in[3];
  const float* q_U = (const float*)d_in[4];
  const float* q_V = (const float*)d_in[5];
  const float* q_b = (const float*)d_in[6];
  const float* k_U = (const float*)d_in[7];
  const float* k_V = (const float*)d_in[8];
  const float* k_b = (const float*)d_in[9];
  const float* v_U = (const float*)d_in[10];
  const float* v_V = (const float*)d_in[11];
  const float* v_b = (const float*)d_in[12];
  const float* out_U = (const float*)d_in[13];
  const float* out_V = (const float*)d_in[14];
  const float* out_b = (const float*)d_in[15];
  const float* ln2_w = (const float*)d_in[16];
  const float* ln2_b = (const float*)d_in[17];
  const float* fc1_U = (const float*)d_in[18];
  const float* fc1_V = (const float*)d_in[19];
  const float* fc1_b = (const float*)d_in[20];
  const float* fc2_U = (const float*)d_in[21];
  const float* fc2_V = (const float*)d_in[22];
  const float* fc2_b = (const float*)d_in[23];
  float* out = (float*)d_out;

  // ---- workspace layout ----
  char* wsb = (char*)d_ws;
  auto US = [&](size_t mb) { return (unsigned short*)(wsb + mb * 1024 * 1024); };
  unsigned short* WqkvT = US(0);    // 1536x1024 bf16  (3MB)
  unsigned short* outUT = US(3);
  unsigned short* outVT = US(4);
  unsigned short* fc1UT = US(5);
  unsigned short* fc1VT = US(6);    // 4096x512 (4MB)
  unsigned short* fc2UT = US(10);   // 512x4096 (4MB)
  unsigned short* fc2VT = US(14);
  unsigned short* xb    = US(15);   // 4096x1024 (8MB)
  unsigned short* Pqkv  = US(23);   // 4096x1536 (12MB) — dead after pv; reused for Vt
  unsigned short* Vt    = US(23);   // (B,H,DH,S) 8MB, overlaps Pqkv (ok: after pv)
  unsigned short* Qb    = US(35);   // (B,H,S,DH) 8MB
  unsigned short* Kb    = US(43);
  unsigned short* Vb    = US(51);
  unsigned short* Yb    = US(59);   // 4096x1024 (8MB)
  unsigned short* Tb    = US(67);   // 4096x512 (4MB)
  float*          hb    = (float*)(wsb + 71ull * 1024 * 1024);  // 16MB
  unsigned short* ab    = US(87);   // 4096x4096 (32MB) -> ends 119MB

  // ---- 1. weight transposes (f32 -> bf16 N x K) ----
  transpose_cvt<<<dim3(512 / 32, 1024 / 32), 256, 0, stream>>>(q_U, WqkvT, 1024, 512);
  transpose_cvt<<<dim3(512 / 32, 1024 / 32), 256, 0, stream>>>(k_U, WqkvT + 512 * 1024, 1024, 512);
  transpose_cvt<<<dim3(512 / 32, 1024 / 32), 256, 0, stream>>>(v_U, WqkvT + 1024 * 1024, 1024, 512);
  transpose_cvt<<<dim3(512 / 32, 1024 / 32), 256, 0, stream>>>(out_U, outUT, 1024, 512);
  transpose_cvt<<<dim3(1024 / 32, 512 / 32), 256, 0, stream>>>(out_V, outVT, 512, 1024);
  transpose_cvt<<<dim3(512 / 32, 1024 / 32), 256, 0, stream>>>(fc1_U, fc1UT, 1024, 512);
  transpose_cvt<<<dim3(4096 / 32, 512 / 32), 256, 0, stream>>>(fc1_V, fc1VT, 512, 4096);
  transpose_cvt<<<dim3(512 / 32, 4096 / 32), 256, 0, stream>>>(fc2_U, fc2UT, 4096, 512);
  transpose_cvt<<<dim3(1024 / 32, 512 / 32), 256, 0, stream>>>(fc2_V, fc2VT, 512, 1024);

  // ---- 2. LN1 -> xb (bf16) ----
  ln_kernel<<<Nt, 256, 0, stream>>>(hidden, ln1_w, ln1_b, xb);
  // ---- 3. batched QKV rank projection ----
  gemm_bf<true, 0, false, false><<<dim3(NP3 / 128, Nt / 128), 256, 0, stream>>>(
      xb, WqkvT, nullptr, nullptr, Pqkv, Nt, NP3, Dc);
  // ---- 4. per-head R->DH (+bias) -> Q,K,V (B,H,S,DH) bf16 ----
  int pvBlocks = Nt * Hc * DHc / 256;
  pv_kernel<<<pvBlocks, 256, 0, stream>>>(Pqkv, q_V, q_b, Qb, 0);
  pv_kernel<<<pvBlocks, 256, 0, stream>>>(Pqkv, k_V, k_b, Kb, 512);
  pv_kernel<<<pvBlocks, 256, 0, stream>>>(Pqkv, v_V, v_b, Vb, 1024);
  // ---- 4b. V -> V^T (B,H,DH,S) (Pqkv region is dead now) ----
  transpose_hd<<<dim3(Sc / 32, 2, Bc * Hc), 256, 0, stream>>>(Vb, Vt);
  // ---- 5. attention -> Yb (B,S,D) bf16 ----
  attn_kernel<<<Bc * Hc * (Sc / 64), 256, 0, stream>>>(Qb, Kb, Vt, Yb);
  // ---- 6. out-proj ----
  gemm_bf<true, 0, false, false><<<dim3(512 / 128, Nt / 128), 256, 0, stream>>>(
      Yb, outUT, nullptr, nullptr, Tb, Nt, 512, Dc);
  gemm_bf<false, 0, true, true><<<dim3(Dc / 128, Nt / 128), 256, 0, stream>>>(
      Tb, outVT, out_b, hidden, hb, Nt, Dc, 512);
  // ---- 7. LN2 -> xb (bf16) ----
  ln_kernel<<<Nt, 256, 0, stream>>>(hb, ln2_w, ln2_b, xb);
  // ---- 8. MLP ----
  gemm_bf<true, 0, false, false><<<dim3(512 / 128, Nt / 128), 256, 0, stream>>>(
      xb, fc1UT, nullptr, nullptr, Tb, Nt, 512, Dc);
  gemm_bf<true, 1, true, false><<<dim3(4096 / 128, Nt / 128), 256, 0, stream>>>(
      Tb, fc1VT, fc1_b, nullptr, ab, Nt, 4096, 512);
  gemm_bf<true, 0, false, false><<<dim3(512 / 128, Nt / 128), 256, 0, stream>>>(
      ab, fc2UT, nullptr, nullptr, Tb, Nt, 512, 4096);
  gemm_bf<false, 0, true, true><<<dim3(Dc / 128, Nt / 128), 256, 0, stream>>>(
      Tb, fc2VT, fc2_b, hb, out, Nt, Dc, 512);
}

// Round 10
// 557.377 us; speedup vs baseline: 27.6887x; 1.0711x over previous
//
#include <hip/hip_runtime.h>
#include <math.h>

// ---------------- problem constants ----------------
constexpr int Bc = 2, Sc = 2048, Dc = 1024, Hc = 16, DHc = 64, Rc = 32;
constexpr int Nt = Bc * Sc;  // 4096 tokens
constexpr int NP3 = 1536;    // batched qkv rank width

typedef __attribute__((ext_vector_type(8))) short bf16x8;
typedef __attribute__((ext_vector_type(4))) float f32x4;

// ---------------- bf16 helpers (raw ushort storage) ----------------
__device__ __forceinline__ unsigned short f2bf(float f) {
  unsigned u = __float_as_uint(f);
  u += 0x7fffu + ((u >> 16) & 1u);  // RNE
  return (unsigned short)(u >> 16);
}
__device__ __forceinline__ float bf2f(unsigned short h) {
  return __uint_as_float(((unsigned)h) << 16);
}

#define GLOAD_LDS16(gp, lp)                                                    \
  __builtin_amdgcn_global_load_lds(                                            \
      (const __attribute__((address_space(1))) void*)(gp),                     \
      (__attribute__((address_space(3))) void*)(lp), 16, 0, 0)

// ---------------- LayerNorm (f32 in, bf16 out) ----------------
__global__ __launch_bounds__(256) void ln_kernel(
    const float* __restrict__ X, const float* __restrict__ w,
    const float* __restrict__ b, unsigned short* __restrict__ Out) {
  int row = blockIdx.x;
  const float* x = X + (size_t)row * Dc;
  unsigned short* o = Out + (size_t)row * Dc;
  int tid = threadIdx.x;
  float4 v = ((const float4*)x)[tid];
  float s  = v.x + v.y + v.z + v.w;
  float sq = v.x * v.x + v.y * v.y + v.z * v.z + v.w * v.w;
#pragma unroll
  for (int off = 32; off; off >>= 1) {
    s  += __shfl_down(s, off);
    sq += __shfl_down(sq, off);
  }
  __shared__ float rs[4], rq[4];
  int wid = tid >> 6, lane = tid & 63;
  if (lane == 0) { rs[wid] = s; rq[wid] = sq; }
  __syncthreads();
  float ts = rs[0] + rs[1] + rs[2] + rs[3];
  float tq = rq[0] + rq[1] + rq[2] + rq[3];
  float mean = ts * (1.f / Dc);
  float var  = tq * (1.f / Dc) - mean * mean;
  float rstd = rsqrtf(var + 1e-5f);
  float4 wv = ((const float4*)w)[tid];
  float4 bv = ((const float4*)b)[tid];
  ushort4 ov;
  ov.x = f2bf((v.x - mean) * rstd * wv.x + bv.x);
  ov.y = f2bf((v.y - mean) * rstd * wv.y + bv.y);
  ov.z = f2bf((v.z - mean) * rstd * wv.z + bv.z);
  ov.w = f2bf((v.w - mean) * rstd * wv.w + bv.w);
  ((ushort4*)o)[tid] = ov;
}

// ---------------- transpose + cvt: in R x C f32 -> out C x R bf16 ----------
__global__ __launch_bounds__(256) void transpose_cvt(
    const float* __restrict__ in, unsigned short* __restrict__ out,
    int R, int C) {
  __shared__ float t[32][33];
  int tx = threadIdx.x & 31, ty = threadIdx.x >> 5;  // ty 0..7
  int r0 = blockIdx.y * 32, c0 = blockIdx.x * 32;
#pragma unroll
  for (int i = 0; i < 4; ++i)
    t[ty + i * 8][tx] = in[(size_t)(r0 + ty + i * 8) * C + c0 + tx];
  __syncthreads();
#pragma unroll
  for (int i = 0; i < 4; ++i)
    out[(size_t)(c0 + ty + i * 8) * R + r0 + tx] = f2bf(t[tx][ty + i * 8]);
}

// ---------------- bf16 transpose (B,H,S,DH) -> (B,H,DH,S) ----------------
__global__ __launch_bounds__(256) void transpose_hd(
    const unsigned short* __restrict__ in, unsigned short* __restrict__ out) {
  __shared__ unsigned short t[32][33];
  int bh = blockIdx.z;
  int s0 = blockIdx.x * 32, e0 = blockIdx.y * 32;
  int tx = threadIdx.x & 31, ty = threadIdx.x >> 5;
  const unsigned short* ib = in + ((size_t)bh * Sc + s0) * 64 + e0;
  unsigned short* ob = out + ((size_t)bh * 64 + e0) * Sc + s0;
#pragma unroll
  for (int i = 0; i < 4; ++i)
    t[ty + i * 8][tx] = ib[(size_t)(ty + i * 8) * 64 + tx];
  __syncthreads();
#pragma unroll
  for (int i = 0; i < 4; ++i)
    ob[(size_t)(ty + i * 8) * Sc + tx] = t[tx][ty + i * 8];
}

// ---------------- bf16 MFMA GEMM (m97 structure, BN=128) ----------------
__device__ __forceinline__ float gelu_f(float v) {
  float c = v + 0.044715f * v * v * v;
  return 0.5f * v * (1.f + tanhf(0.7978845608028654f * c));
}

template <bool OBF16, int ACT, bool BIAS, bool RES>
__global__ __launch_bounds__(256) void gemm_bf(
    const unsigned short* __restrict__ A, const unsigned short* __restrict__ BT,
    const float* __restrict__ bias, const float* __restrict__ res,
    void* __restrict__ Cv, int M, int N, int K) {
  __shared__ unsigned short As[128 * 32];
  __shared__ unsigned short Bs[128 * 32];
  int tid = threadIdx.x;
  int lane = tid & 63, wv = tid >> 6;
  int bm = blockIdx.y * 128, bn = blockIdx.x * 128;
  int wr = wv >> 1, wc = wv & 1;
  f32x4 acc[4][4] = {};
  int soff0 = wv * 512 + lane * 8;
  int soff1 = soff0 + 2048;
  int ar0 = soff0 >> 5, ak0 = soff0 & 31;
  int ar1 = soff1 >> 5, ak1 = soff1 & 31;
  const unsigned short* Ab = A + (size_t)bm * K;
  const unsigned short* Bb = BT + (size_t)bn * K;
  for (int k0 = 0; k0 < K; k0 += 32) {
    __syncthreads();
    GLOAD_LDS16(Ab + (size_t)ar0 * K + k0 + ak0, As + wv * 512);
    GLOAD_LDS16(Ab + (size_t)ar1 * K + k0 + ak1, As + 2048 + wv * 512);
    GLOAD_LDS16(Bb + (size_t)ar0 * K + k0 + ak0, Bs + wv * 512);
    GLOAD_LDS16(Bb + (size_t)ar1 * K + k0 + ak1, Bs + 2048 + wv * 512);
    __syncthreads();
    bf16x8 af[4], bf[4];
#pragma unroll
    for (int m = 0; m < 4; ++m)
      af[m] = *(const bf16x8*)&As[(wr * 64 + m * 16 + (lane & 15)) * 32 + (lane >> 4) * 8];
#pragma unroll
    for (int n = 0; n < 4; ++n)
      bf[n] = *(const bf16x8*)&Bs[(wc * 64 + n * 16 + (lane & 15)) * 32 + (lane >> 4) * 8];
#pragma unroll
    for (int m = 0; m < 4; ++m)
#pragma unroll
      for (int n = 0; n < 4; ++n)
        acc[m][n] = __builtin_amdgcn_mfma_f32_16x16x32_bf16(af[m], bf[n], acc[m][n], 0, 0, 0);
  }
  int cg = lane >> 4;
#pragma unroll
  for (int m = 0; m < 4; ++m) {
#pragma unroll
    for (int n = 0; n < 4; ++n) {
      int row0 = bm + wr * 64 + m * 16 + cg * 4;
      int col  = bn + wc * 64 + n * 16 + (lane & 15);
      float bb = BIAS ? bias[col] : 0.f;
#pragma unroll
      for (int i = 0; i < 4; ++i) {
        float v = acc[m][n][i];
        if (BIAS) v += bb;
        if (ACT == 1) v = gelu_f(v);
        if (RES) v += res[(size_t)(row0 + i) * N + col];
        if (OBF16)
          ((unsigned short*)Cv)[(size_t)(row0 + i) * N + col] = f2bf(v);
        else
          ((float*)Cv)[(size_t)(row0 + i) * N + col] = v;
      }
    }
  }
}

// ---------------- bf16 MFMA GEMM, BN=64 (for N=512 outputs) ---------------
// 128x64 tile, 4 waves stacked in M (wave wv owns rows wv*32..+32, all 64 cols)
template <bool OBF16, int ACT, bool BIAS, bool RES>
__global__ __launch_bounds__(256) void gemm_bf_n64(
    const unsigned short* __restrict__ A, const unsigned short* __restrict__ BT,
    const float* __restrict__ bias, const float* __restrict__ res,
    void* __restrict__ Cv, int M, int N, int K) {
  __shared__ unsigned short As[128 * 32];
  __shared__ unsigned short Bs[64 * 32];
  int tid = threadIdx.x;
  int lane = tid & 63, wv = tid >> 6;
  int bm = blockIdx.y * 128, bn = blockIdx.x * 64;
  f32x4 acc[2][4] = {};
  int soff0 = wv * 512 + lane * 8;
  int soff1 = soff0 + 2048;
  int ar0 = soff0 >> 5, ak0 = soff0 & 31;
  int ar1 = soff1 >> 5, ak1 = soff1 & 31;
  const unsigned short* Ab = A + (size_t)bm * K;
  const unsigned short* Bb = BT + (size_t)bn * K;
  int c = lane & 15, g = lane >> 4;
  for (int k0 = 0; k0 < K; k0 += 32) {
    __syncthreads();
    GLOAD_LDS16(Ab + (size_t)ar0 * K + k0 + ak0, As + wv * 512);
    GLOAD_LDS16(Ab + (size_t)ar1 * K + k0 + ak1, As + 2048 + wv * 512);
    GLOAD_LDS16(Bb + (size_t)ar0 * K + k0 + ak0, Bs + wv * 512);
    __syncthreads();
    bf16x8 af[2], bfr[4];
#pragma unroll
    for (int m = 0; m < 2; ++m)
      af[m] = *(const bf16x8*)&As[(wv * 32 + m * 16 + c) * 32 + g * 8];
#pragma unroll
    for (int n = 0; n < 4; ++n)
      bfr[n] = *(const bf16x8*)&Bs[(n * 16 + c) * 32 + g * 8];
#pragma unroll
    for (int m = 0; m < 2; ++m)
#pragma unroll
      for (int n = 0; n < 4; ++n)
        acc[m][n] = __builtin_amdgcn_mfma_f32_16x16x32_bf16(af[m], bfr[n], acc[m][n], 0, 0, 0);
  }
#pragma unroll
  for (int m = 0; m < 2; ++m) {
#pragma unroll
    for (int n = 0; n < 4; ++n) {
      int row0 = bm + wv * 32 + m * 16 + g * 4;
      int col  = bn + n * 16 + c;
      float bb = BIAS ? bias[col] : 0.f;
#pragma unroll
      for (int i = 0; i < 4; ++i) {
        float v = acc[m][n][i];
        if (BIAS) v += bb;
        if (ACT == 1) v = gelu_f(v);
        if (RES) v += res[(size_t)(row0 + i) * N + col];
        if (OBF16)
          ((unsigned short*)Cv)[(size_t)(row0 + i) * N + col] = f2bf(v);
        else
          ((float*)Cv)[(size_t)(row0 + i) * N + col] = v;
      }
    }
  }
}

// ---------------- fused per-head rank->head projection (Q,K,V in one) ------
__global__ __launch_bounds__(256) void pv3_kernel(
    const unsigned short* __restrict__ P,
    const float* __restrict__ qV, const float* __restrict__ kV,
    const float* __restrict__ vV, const float* __restrict__ qb,
    const float* __restrict__ kb, const float* __restrict__ vb,
    unsigned short* __restrict__ Qb, unsigned short* __restrict__ Kb,
    unsigned short* __restrict__ Vb) {
  int which = blockIdx.y;
  const float* Vw = which == 0 ? qV : which == 1 ? kV : vV;
  const float* bias = which == 0 ? qb : which == 1 ? kb : vb;
  unsigned short* Out = which == 0 ? Qb : which == 1 ? Kb : Vb;
  int colOff = which * 512;
  int idx = blockIdx.x * 256 + threadIdx.x;
  int e = idx & 63;
  int h = (idx >> 6) & 15;
  int n = idx >> 10;
  const unsigned short* prow = P + (size_t)n * NP3 + colOff + h * Rc;
  const float* vcol = Vw + h * (Rc * DHc) + e;
  float acc = 0.f;
#pragma unroll
  for (int r = 0; r < Rc; ++r) acc = fmaf(bf2f(prow[r]), vcol[r * DHc], acc);
  acc += bias[(h << 6) + e];
  int b = n / Sc, s = n % Sc;
  Out[(((size_t)(b * Hc + h) * Sc + s) << 6) + e] = f2bf(acc);
}

// ---------------- causal flash attention (MFMA, double-buffered K/V) -------
// block = (bh, 64-row q-tile), 4 waves; wave w owns q rows [qbase+w*16, +16).
// K staged row-major [key][d], V staged TRANSPOSED [d][key]; both XOR-swizzled
// (16B slot index ^= row&7) via pre-swizzled global_load_lds source (m173).
// Double-buffer: issue stage(kt+1) into buf^1 right after the barrier, then
// compute buf — the NEXT iteration's barrier (implicit vmcnt(0)) drains it.
__global__ __launch_bounds__(256) void attn_kernel(
    const unsigned short* __restrict__ Q, const unsigned short* __restrict__ K,
    const unsigned short* __restrict__ VT, unsigned short* __restrict__ Y) {
  __shared__ unsigned short Ks[2][64 * 64];
  __shared__ unsigned short Vs[2][64 * 64];
  __shared__ unsigned short Ps[4][16 * 64];
  int bid = blockIdx.x;
  int bh = bid >> 5;
  int qt = 31 - (bid & 31);  // big tiles first
  int qbase = qt * 64;
  int tid = threadIdx.x, lane = tid & 63, w = tid >> 6;
  int g = lane >> 4, c = lane & 15;
  const unsigned short* Qg = Q + (size_t)bh * Sc * 64;
  const unsigned short* Kg = K + (size_t)bh * Sc * 64;
  const unsigned short* Vg = VT + (size_t)bh * 64 * Sc;
  // Q fragments (A-layout: row=c, k=g*8+j), d-halves 0 / 32
  int q0 = qbase + w * 16;
  bf16x8 qa0 = *(const bf16x8*)(Qg + (size_t)(q0 + c) * 64 + g * 8);
  bf16x8 qa1 = *(const bf16x8*)(Qg + (size_t)(q0 + c) * 64 + 32 + g * 8);
  f32x4 O0 = {0.f, 0.f, 0.f, 0.f}, O1 = O0, O2 = O0, O3 = O0;
  float m[4] = {-1e30f, -1e30f, -1e30f, -1e30f};
  float l[4] = {0.f, 0.f, 0.f, 0.f};
  // staging source precompute: LDS linear slot (r, sl) holds key-block sl^(r&7)
  int r0s = tid >> 3;               // rows 0..31 (call 0)
  int b0s = (tid & 7) ^ (r0s & 7);  // source 16B block
  int r1s = (256 + tid) >> 3;       // rows 32..63 (call 1)
  int b1s = (tid & 7) ^ (r1s & 7);
  size_t kOff0 = (size_t)r0s * 64 + b0s * 8;
  size_t kOff1 = (size_t)r1s * 64 + b1s * 8;
  size_t vOff0 = (size_t)r0s * Sc + b0s * 8;
  size_t vOff1 = (size_t)r1s * Sc + b1s * 8;
  unsigned short* Pw = Ps[w];
  const f32x4 zero = {0.f, 0.f, 0.f, 0.f};
  int swc = c & 7;
  int wOff = w * 512;

#define STAGE(kt_, buf_)                                                       \
  {                                                                            \
    const unsigned short* Kt_ = Kg + (size_t)(kt_) * 64 * 64;                  \
    const unsigned short* Vt_ = Vg + (size_t)(kt_) * 64;                       \
    GLOAD_LDS16(Kt_ + kOff0, &Ks[buf_][wOff]);                                 \
    GLOAD_LDS16(Kt_ + kOff1, &Ks[buf_][2048 + wOff]);                          \
    GLOAD_LDS16(Vt_ + vOff0, &Vs[buf_][wOff]);                                 \
    GLOAD_LDS16(Vt_ + vOff1, &Vs[buf_][2048 + wOff]);                          \
  }

  STAGE(0, 0);  // prologue
  for (int kt = 0; kt <= qt; ++kt) {
    int buf = kt & 1;
    // barrier: (a) drains this wave's outstanding global_load_lds (vmcnt 0)
    // so Ks/Vs[buf] is complete; (b) all waves done reading buf^1 (kt-1).
    __syncthreads();
    if (kt < qt) STAGE(kt + 1, buf ^ 1);  // async prefetch into other buffer
    const unsigned short* Ksb = Ks[buf];
    const unsigned short* Vsb = Vs[buf];
    // ---- scores: S[q=4g+i][key=kb*16+c] via 2 MFMA per key-block
    f32x4 sA[4];
#pragma unroll
    for (int kb = 0; kb < 4; ++kb) {
      int keyr = kb * 16 + c;
      int sw = keyr & 7;
      bf16x8 k0 = *(const bf16x8*)&Ksb[keyr * 64 + ((g ^ sw) << 3)];
      bf16x8 k1 = *(const bf16x8*)&Ksb[keyr * 64 + (((4 + g) ^ sw) << 3)];
      f32x4 a = __builtin_amdgcn_mfma_f32_16x16x32_bf16(qa0, k0, zero, 0, 0, 0);
      a = __builtin_amdgcn_mfma_f32_16x16x32_bf16(qa1, k1, a, 0, 0, 0);
      sA[kb] = a;
    }
    // ---- scale + causal mask + online softmax (rows spread over 16-lane grp)
    float p[4][4], rm[4];
#pragma unroll
    for (int i = 0; i < 4; ++i) rm[i] = -1e30f;
#pragma unroll
    for (int kb = 0; kb < 4; ++kb)
#pragma unroll
      for (int i = 0; i < 4; ++i) {
        float s = sA[kb][i] * 0.125f;
        if (kt == qt && (kb * 16 + c) > (w * 16 + 4 * g + i)) s = -1e30f;
        p[kb][i] = s;
        rm[i] = fmaxf(rm[i], s);
      }
#pragma unroll
    for (int i = 0; i < 4; ++i) {
      rm[i] = fmaxf(rm[i], __shfl_xor(rm[i], 1));
      rm[i] = fmaxf(rm[i], __shfl_xor(rm[i], 2));
      rm[i] = fmaxf(rm[i], __shfl_xor(rm[i], 4));
      rm[i] = fmaxf(rm[i], __shfl_xor(rm[i], 8));
    }
    float sc[4], ls[4];
#pragma unroll
    for (int i = 0; i < 4; ++i) {
      float mn = fmaxf(m[i], rm[i]);
      sc[i] = __expf(m[i] - mn);
      m[i] = mn;
      ls[i] = 0.f;
    }
#pragma unroll
    for (int kb = 0; kb < 4; ++kb)
#pragma unroll
      for (int i = 0; i < 4; ++i) {
        float e = __expf(p[kb][i] - m[i]);
        p[kb][i] = e;
        ls[i] += e;
      }
#pragma unroll
    for (int i = 0; i < 4; ++i) {
      ls[i] += __shfl_xor(ls[i], 1);
      ls[i] += __shfl_xor(ls[i], 2);
      ls[i] += __shfl_xor(ls[i], 4);
      ls[i] += __shfl_xor(ls[i], 8);
      l[i] = l[i] * sc[i] + ls[i];
      O0[i] *= sc[i]; O1[i] *= sc[i]; O2[i] *= sc[i]; O3[i] *= sc[i];
    }
    // ---- P -> wave-private swizzled LDS tile (bf16)
#pragma unroll
    for (int kb = 0; kb < 4; ++kb)
#pragma unroll
      for (int i = 0; i < 4; ++i) {
        int row = 4 * g + i;
        int slot = (kb * 2 + (c >> 3)) ^ (row & 7);
        Pw[row * 64 + slot * 8 + (c & 7)] = f2bf(p[kb][i]);
      }
    // ---- PV: O[q][d] += P(16x64) @ V(64x64) ; A-frag from Pw, B-frag from Vs
    bf16x8 pa0 = *(const bf16x8*)&Pw[c * 64 + ((g ^ swc) << 3)];
    bf16x8 pa1 = *(const bf16x8*)&Pw[c * 64 + (((4 + g) ^ swc) << 3)];
#define PV_DB(db, Ov)                                                          \
    {                                                                          \
      int d_ = db * 16 + c;                                                    \
      bf16x8 v0 = *(const bf16x8*)&Vsb[d_ * 64 + ((g ^ swc) << 3)];            \
      bf16x8 v1 = *(const bf16x8*)&Vsb[d_ * 64 + (((4 + g) ^ swc) << 3)];      \
      Ov = __builtin_amdgcn_mfma_f32_16x16x32_bf16(pa0, v0, Ov, 0, 0, 0);      \
      Ov = __builtin_amdgcn_mfma_f32_16x16x32_bf16(pa1, v1, Ov, 0, 0, 0);      \
    }
    PV_DB(0, O0) PV_DB(1, O1) PV_DB(2, O2) PV_DB(3, O3)
#undef PV_DB
  }
#undef STAGE
  // ---- epilogue: Y[(b, q, h*64+d)] = O/l
  float inv[4];
#pragma unroll
  for (int i = 0; i < 4; ++i) inv[i] = 1.f / l[i];
  int b = bh >> 4, h = bh & 15;
#define WR_DB(db, Ov)                                                          \
  {                                                                            \
    _Pragma("unroll")                                                          \
    for (int i = 0; i < 4; ++i) {                                              \
      int q_ = q0 + 4 * g + i;                                                 \
      Y[(size_t)(b * Sc + q_) * Dc + h * 64 + db * 16 + c] =                   \
          f2bf(Ov[i] * inv[i]);                                                \
    }                                                                          \
  }
  WR_DB(0, O0) WR_DB(1, O1) WR_DB(2, O2) WR_DB(3, O3)
#undef WR_DB
}

// ---------------- launch ----------------
extern "C" void kernel_launch(void* const* d_in, const int* in_sizes, int n_in,
                              void* d_out, int out_size, void* d_ws, size_t ws_size,
                              hipStream_t stream) {
  const float* hidden = (const float*)d_in[0];
  const float* ln1_w = (const float*)d_in[2];
  const float* ln1_b = (const float*)d_in[3];
  const float* q_U = (const float*)d_in[4];
  const float* q_V = (const float*)d_in[5];
  const float* q_b = (const float*)d_in[6];
  const float* k_U = (const float*)d_in[7];
  const float* k_V = (const float*)d_in[8];
  const float* k_b = (const float*)d_in[9];
  const float* v_U = (const float*)d_in[10];
  const float* v_V = (const float*)d_in[11];
  const float* v_b = (const float*)d_in[12];
  const float* out_U = (const float*)d_in[13];
  const float* out_V = (const float*)d_in[14];
  const float* out_b = (const float*)d_in[15];
  const float* ln2_w = (const float*)d_in[16];
  const float* ln2_b = (const float*)d_in[17];
  const float* fc1_U = (const float*)d_in[18];
  const float* fc1_V = (const float*)d_in[19];
  const float* fc1_b = (const float*)d_in[20];
  const float* fc2_U = (const float*)d_in[21];
  const float* fc2_V = (const float*)d_in[22];
  const float* fc2_b = (const float*)d_in[23];
  float* out = (float*)d_out;

  // ---- workspace layout ----
  char* wsb = (char*)d_ws;
  auto US = [&](size_t mb) { return (unsigned short*)(wsb + mb * 1024 * 1024); };
  unsigned short* WqkvT = US(0);    // 1536x1024 bf16  (3MB)
  unsigned short* outUT = US(3);
  unsigned short* outVT = US(4);
  unsigned short* fc1UT = US(5);
  unsigned short* fc1VT = US(6);    // 4096x512 (4MB)
  unsigned short* fc2UT = US(10);   // 512x4096 (4MB)
  unsigned short* fc2VT = US(14);
  unsigned short* xb    = US(15);   // 4096x1024 (8MB)
  unsigned short* Pqkv  = US(23);   // 4096x1536 (12MB) — dead after pv; reused for Vt
  unsigned short* Vt    = US(23);   // (B,H,DH,S) 8MB, overlaps Pqkv (ok: after pv)
  unsigned short* Qb    = US(35);   // (B,H,S,DH) 8MB
  unsigned short* Kb    = US(43);
  unsigned short* Vb    = US(51);
  unsigned short* Yb    = US(59);   // 4096x1024 (8MB)
  unsigned short* Tb    = US(67);   // 4096x512 (4MB)
  float*          hb    = (float*)(wsb + 71ull * 1024 * 1024);  // 16MB
  unsigned short* ab    = US(87);   // 4096x4096 (32MB) -> ends 119MB

  // ---- 1. weight transposes (f32 -> bf16 N x K) ----
  transpose_cvt<<<dim3(512 / 32, 1024 / 32), 256, 0, stream>>>(q_U, WqkvT, 1024, 512);
  transpose_cvt<<<dim3(512 / 32, 1024 / 32), 256, 0, stream>>>(k_U, WqkvT + 512 * 1024, 1024, 512);
  transpose_cvt<<<dim3(512 / 32, 1024 / 32), 256, 0, stream>>>(v_U, WqkvT + 1024 * 1024, 1024, 512);
  transpose_cvt<<<dim3(512 / 32, 1024 / 32), 256, 0, stream>>>(out_U, outUT, 1024, 512);
  transpose_cvt<<<dim3(1024 / 32, 512 / 32), 256, 0, stream>>>(out_V, outVT, 512, 1024);
  transpose_cvt<<<dim3(512 / 32, 1024 / 32), 256, 0, stream>>>(fc1_U, fc1UT, 1024, 512);
  transpose_cvt<<<dim3(4096 / 32, 512 / 32), 256, 0, stream>>>(fc1_V, fc1VT, 512, 4096);
  transpose_cvt<<<dim3(512 / 32, 4096 / 32), 256, 0, stream>>>(fc2_U, fc2UT, 4096, 512);
  transpose_cvt<<<dim3(1024 / 32, 512 / 32), 256, 0, stream>>>(fc2_V, fc2VT, 512, 1024);

  // ---- 2. LN1 -> xb (bf16) ----
  ln_kernel<<<Nt, 256, 0, stream>>>(hidden, ln1_w, ln1_b, xb);
  // ---- 3. batched QKV rank projection ----
  gemm_bf<true, 0, false, false><<<dim3(NP3 / 128, Nt / 128), 256, 0, stream>>>(
      xb, WqkvT, nullptr, nullptr, Pqkv, Nt, NP3, Dc);
  // ---- 4. per-head R->DH (+bias) -> Q,K,V (B,H,S,DH) bf16, one launch ----
  int pvBlocks = Nt * Hc * DHc / 256;
  pv3_kernel<<<dim3(pvBlocks, 3), 256, 0, stream>>>(
      Pqkv, q_V, k_V, v_V, q_b, k_b, v_b, Qb, Kb, Vb);
  // ---- 4b. V -> V^T (B,H,DH,S) (Pqkv region is dead now) ----
  transpose_hd<<<dim3(Sc / 32, 2, Bc * Hc), 256, 0, stream>>>(Vb, Vt);
  // ---- 5. attention -> Yb (B,S,D) bf16 ----
  attn_kernel<<<Bc * Hc * (Sc / 64), 256, 0, stream>>>(Qb, Kb, Vt, Yb);
  // ---- 6. out-proj (N=512 GEMM uses BN=64 grid for full CU coverage) ----
  gemm_bf_n64<true, 0, false, false><<<dim3(512 / 64, Nt / 128), 256, 0, stream>>>(
      Yb, outUT, nullptr, nullptr, Tb, Nt, 512, Dc);
  gemm_bf<false, 0, true, true><<<dim3(Dc / 128, Nt / 128), 256, 0, stream>>>(
      Tb, outVT, out_b, hidden, hb, Nt, Dc, 512);
  // ---- 7. LN2 -> xb (bf16) ----
  ln_kernel<<<Nt, 256, 0, stream>>>(hb, ln2_w, ln2_b, xb);
  // ---- 8. MLP ----
  gemm_bf_n64<true, 0, false, false><<<dim3(512 / 64, Nt / 128), 256, 0, stream>>>(
      xb, fc1UT, nullptr, nullptr, Tb, Nt, 512, Dc);
  gemm_bf<true, 1, true, false><<<dim3(4096 / 128, Nt / 128), 256, 0, stream>>>(
      Tb, fc1VT, fc1_b, nullptr, ab, Nt, 4096, 512);
  gemm_bf_n64<true, 0, false, false><<<dim3(512 / 64, Nt / 128), 256, 0, stream>>>(
      ab, fc2UT, nullptr, nullptr, Tb, Nt, 512, 4096);
  gemm_bf<false, 0, true, true><<<dim3(Dc / 128, Nt / 128), 256, 0, stream>>>(
      Tb, fc2VT, fc2_b, hb, out, Nt, Dc, 512);
}

// Round 11
// 484.592 us; speedup vs baseline: 31.8475x; 1.1502x over previous
//
#include <hip/hip_runtime.h>
#include <math.h>

// ---------------- problem constants ----------------
constexpr int Bc = 2, Sc = 2048, Dc = 1024, Hc = 16, DHc = 64, Rc = 32;
constexpr int Nt = Bc * Sc;  // 4096 tokens
constexpr int NP3 = 1536;    // batched qkv rank width

typedef __attribute__((ext_vector_type(8))) short bf16x8;
typedef __attribute__((ext_vector_type(4))) float f32x4;

// ---------------- bf16 helpers (raw ushort storage) ----------------
__device__ __forceinline__ unsigned short f2bf(float f) {
  unsigned u = __float_as_uint(f);
  u += 0x7fffu + ((u >> 16) & 1u);  // RNE
  return (unsigned short)(u >> 16);
}
__device__ __forceinline__ float bf2f(unsigned short h) {
  return __uint_as_float(((unsigned)h) << 16);
}

#define GLOAD_LDS16(gp, lp)                                                    \
  __builtin_amdgcn_global_load_lds(                                            \
      (const __attribute__((address_space(1))) void*)(gp),                     \
      (__attribute__((address_space(3))) void*)(lp), 16, 0, 0)

// ---------------- LayerNorm (f32 in, bf16 out) ----------------
__global__ __launch_bounds__(256) void ln_kernel(
    const float* __restrict__ X, const float* __restrict__ w,
    const float* __restrict__ b, unsigned short* __restrict__ Out) {
  int row = blockIdx.x;
  const float* x = X + (size_t)row * Dc;
  unsigned short* o = Out + (size_t)row * Dc;
  int tid = threadIdx.x;
  float4 v = ((const float4*)x)[tid];
  float s  = v.x + v.y + v.z + v.w;
  float sq = v.x * v.x + v.y * v.y + v.z * v.z + v.w * v.w;
#pragma unroll
  for (int off = 32; off; off >>= 1) {
    s  += __shfl_down(s, off);
    sq += __shfl_down(sq, off);
  }
  __shared__ float rs[4], rq[4];
  int wid = tid >> 6, lane = tid & 63;
  if (lane == 0) { rs[wid] = s; rq[wid] = sq; }
  __syncthreads();
  float ts = rs[0] + rs[1] + rs[2] + rs[3];
  float tq = rq[0] + rq[1] + rq[2] + rq[3];
  float mean = ts * (1.f / Dc);
  float var  = tq * (1.f / Dc) - mean * mean;
  float rstd = rsqrtf(var + 1e-5f);
  float4 wv = ((const float4*)w)[tid];
  float4 bv = ((const float4*)b)[tid];
  ushort4 ov;
  ov.x = f2bf((v.x - mean) * rstd * wv.x + bv.x);
  ov.y = f2bf((v.y - mean) * rstd * wv.y + bv.y);
  ov.z = f2bf((v.z - mean) * rstd * wv.z + bv.z);
  ov.w = f2bf((v.w - mean) * rstd * wv.w + bv.w);
  ((ushort4*)o)[tid] = ov;
}

// ---------------- fused transpose+cvt for all 9 weight matrices ------------
// out[c][r] = bf16(in[r][c]) for each descriptor; one dispatch.
struct TransArgs {
  const float* src[9];
  unsigned short* dst[9];
  int R[9], C[9];
  int bstart[10];
};

__global__ __launch_bounds__(256) void transpose_cvt_all(TransArgs a) {
  __shared__ float t[32][33];
  int bid = blockIdx.x;
  int mi = 0;
#pragma unroll
  for (int i = 1; i < 9; ++i)
    if (bid >= a.bstart[i]) mi = i;
  const float* src = a.src[mi];
  unsigned short* dst = a.dst[mi];
  int R = a.R[mi], C = a.C[mi];
  int lb = bid - a.bstart[mi];
  int cb = C >> 5;
  int by = lb / cb, bx = lb - by * cb;
  int tx = threadIdx.x & 31, ty = threadIdx.x >> 5;  // ty 0..7
  int r0 = by * 32, c0 = bx * 32;
#pragma unroll
  for (int i = 0; i < 4; ++i)
    t[ty + i * 8][tx] = src[(size_t)(r0 + ty + i * 8) * C + c0 + tx];
  __syncthreads();
#pragma unroll
  for (int i = 0; i < 4; ++i)
    dst[(size_t)(c0 + ty + i * 8) * R + r0 + tx] = f2bf(t[tx][ty + i * 8]);
}

// ---------------- bf16 transpose (B,H,S,DH) -> (B,H,DH,S) ----------------
__global__ __launch_bounds__(256) void transpose_hd(
    const unsigned short* __restrict__ in, unsigned short* __restrict__ out) {
  __shared__ unsigned short t[32][33];
  int bh = blockIdx.z;
  int s0 = blockIdx.x * 32, e0 = blockIdx.y * 32;
  int tx = threadIdx.x & 31, ty = threadIdx.x >> 5;
  const unsigned short* ib = in + ((size_t)bh * Sc + s0) * 64 + e0;
  unsigned short* ob = out + ((size_t)bh * 64 + e0) * Sc + s0;
#pragma unroll
  for (int i = 0; i < 4; ++i)
    t[ty + i * 8][tx] = ib[(size_t)(ty + i * 8) * 64 + tx];
  __syncthreads();
#pragma unroll
  for (int i = 0; i < 4; ++i)
    ob[(size_t)(ty + i * 8) * Sc + tx] = t[tx][ty + i * 8];
}

// ---------------- bf16 MFMA GEMM (m97 structure, BN=128) ----------------
__device__ __forceinline__ float gelu_f(float v) {
  float c = v + 0.044715f * v * v * v;
  return 0.5f * v * (1.f + tanhf(0.7978845608028654f * c));
}

template <bool OBF16, int ACT, bool BIAS, bool RES>
__global__ __launch_bounds__(256) void gemm_bf(
    const unsigned short* __restrict__ A, const unsigned short* __restrict__ BT,
    const float* __restrict__ bias, const float* __restrict__ res,
    void* __restrict__ Cv, int M, int N, int K) {
  __shared__ unsigned short As[128 * 32];
  __shared__ unsigned short Bs[128 * 32];
  int tid = threadIdx.x;
  int lane = tid & 63, wv = tid >> 6;
  int bm = blockIdx.y * 128, bn = blockIdx.x * 128;
  int wr = wv >> 1, wc = wv & 1;
  f32x4 acc[4][4] = {};
  int soff0 = wv * 512 + lane * 8;
  int soff1 = soff0 + 2048;
  int ar0 = soff0 >> 5, ak0 = soff0 & 31;
  int ar1 = soff1 >> 5, ak1 = soff1 & 31;
  const unsigned short* Ab = A + (size_t)bm * K;
  const unsigned short* Bb = BT + (size_t)bn * K;
  for (int k0 = 0; k0 < K; k0 += 32) {
    __syncthreads();
    GLOAD_LDS16(Ab + (size_t)ar0 * K + k0 + ak0, As + wv * 512);
    GLOAD_LDS16(Ab + (size_t)ar1 * K + k0 + ak1, As + 2048 + wv * 512);
    GLOAD_LDS16(Bb + (size_t)ar0 * K + k0 + ak0, Bs + wv * 512);
    GLOAD_LDS16(Bb + (size_t)ar1 * K + k0 + ak1, Bs + 2048 + wv * 512);
    __syncthreads();
    bf16x8 af[4], bf[4];
#pragma unroll
    for (int m = 0; m < 4; ++m)
      af[m] = *(const bf16x8*)&As[(wr * 64 + m * 16 + (lane & 15)) * 32 + (lane >> 4) * 8];
#pragma unroll
    for (int n = 0; n < 4; ++n)
      bf[n] = *(const bf16x8*)&Bs[(wc * 64 + n * 16 + (lane & 15)) * 32 + (lane >> 4) * 8];
#pragma unroll
    for (int m = 0; m < 4; ++m)
#pragma unroll
      for (int n = 0; n < 4; ++n)
        acc[m][n] = __builtin_amdgcn_mfma_f32_16x16x32_bf16(af[m], bf[n], acc[m][n], 0, 0, 0);
  }
  int cg = lane >> 4;
#pragma unroll
  for (int m = 0; m < 4; ++m) {
#pragma unroll
    for (int n = 0; n < 4; ++n) {
      int row0 = bm + wr * 64 + m * 16 + cg * 4;
      int col  = bn + wc * 64 + n * 16 + (lane & 15);
      float bb = BIAS ? bias[col] : 0.f;
#pragma unroll
      for (int i = 0; i < 4; ++i) {
        float v = acc[m][n][i];
        if (BIAS) v += bb;
        if (ACT == 1) v = gelu_f(v);
        if (RES) v += res[(size_t)(row0 + i) * N + col];
        if (OBF16)
          ((unsigned short*)Cv)[(size_t)(row0 + i) * N + col] = f2bf(v);
        else
          ((float*)Cv)[(size_t)(row0 + i) * N + col] = v;
      }
    }
  }
}

// ---------------- bf16 MFMA GEMM, BN=64 (for N=512 outputs) ---------------
template <bool OBF16, int ACT, bool BIAS, bool RES>
__global__ __launch_bounds__(256) void gemm_bf_n64(
    const unsigned short* __restrict__ A, const unsigned short* __restrict__ BT,
    const float* __restrict__ bias, const float* __restrict__ res,
    void* __restrict__ Cv, int M, int N, int K) {
  __shared__ unsigned short As[128 * 32];
  __shared__ unsigned short Bs[64 * 32];
  int tid = threadIdx.x;
  int lane = tid & 63, wv = tid >> 6;
  int bm = blockIdx.y * 128, bn = blockIdx.x * 64;
  f32x4 acc[2][4] = {};
  int soff0 = wv * 512 + lane * 8;
  int soff1 = soff0 + 2048;
  int ar0 = soff0 >> 5, ak0 = soff0 & 31;
  int ar1 = soff1 >> 5, ak1 = soff1 & 31;
  const unsigned short* Ab = A + (size_t)bm * K;
  const unsigned short* Bb = BT + (size_t)bn * K;
  int c = lane & 15, g = lane >> 4;
  for (int k0 = 0; k0 < K; k0 += 32) {
    __syncthreads();
    GLOAD_LDS16(Ab + (size_t)ar0 * K + k0 + ak0, As + wv * 512);
    GLOAD_LDS16(Ab + (size_t)ar1 * K + k0 + ak1, As + 2048 + wv * 512);
    GLOAD_LDS16(Bb + (size_t)ar0 * K + k0 + ak0, Bs + wv * 512);
    __syncthreads();
    bf16x8 af[2], bfr[4];
#pragma unroll
    for (int m = 0; m < 2; ++m)
      af[m] = *(const bf16x8*)&As[(wv * 32 + m * 16 + c) * 32 + g * 8];
#pragma unroll
    for (int n = 0; n < 4; ++n)
      bfr[n] = *(const bf16x8*)&Bs[(n * 16 + c) * 32 + g * 8];
#pragma unroll
    for (int m = 0; m < 2; ++m)
#pragma unroll
      for (int n = 0; n < 4; ++n)
        acc[m][n] = __builtin_amdgcn_mfma_f32_16x16x32_bf16(af[m], bfr[n], acc[m][n], 0, 0, 0);
  }
#pragma unroll
  for (int m = 0; m < 2; ++m) {
#pragma unroll
    for (int n = 0; n < 4; ++n) {
      int row0 = bm + wv * 32 + m * 16 + g * 4;
      int col  = bn + n * 16 + c;
      float bb = BIAS ? bias[col] : 0.f;
#pragma unroll
      for (int i = 0; i < 4; ++i) {
        float v = acc[m][n][i];
        if (BIAS) v += bb;
        if (ACT == 1) v = gelu_f(v);
        if (RES) v += res[(size_t)(row0 + i) * N + col];
        if (OBF16)
          ((unsigned short*)Cv)[(size_t)(row0 + i) * N + col] = f2bf(v);
        else
          ((float*)Cv)[(size_t)(row0 + i) * N + col] = v;
      }
    }
  }
}

// ---------------- fused per-head rank->head projection (Q,K,V in one) ------
__global__ __launch_bounds__(256) void pv3_kernel(
    const unsigned short* __restrict__ P,
    const float* __restrict__ qV, const float* __restrict__ kV,
    const float* __restrict__ vV, const float* __restrict__ qb,
    const float* __restrict__ kb, const float* __restrict__ vb,
    unsigned short* __restrict__ Qb, unsigned short* __restrict__ Kb,
    unsigned short* __restrict__ Vb) {
  int which = blockIdx.y;
  const float* Vw = which == 0 ? qV : which == 1 ? kV : vV;
  const float* bias = which == 0 ? qb : which == 1 ? kb : vb;
  unsigned short* Out = which == 0 ? Qb : which == 1 ? Kb : Vb;
  int colOff = which * 512;
  int idx = blockIdx.x * 256 + threadIdx.x;
  int e = idx & 63;
  int h = (idx >> 6) & 15;
  int n = idx >> 10;
  const unsigned short* prow = P + (size_t)n * NP3 + colOff + h * Rc;
  const float* vcol = Vw + h * (Rc * DHc) + e;
  float acc = 0.f;
#pragma unroll
  for (int r = 0; r < Rc; ++r) acc = fmaf(bf2f(prow[r]), vcol[r * DHc], acc);
  acc += bias[(h << 6) + e];
  int b = n / Sc, s = n % Sc;
  Out[(((size_t)(b * Hc + h) * Sc + s) << 6) + e] = f2bf(acc);
}

// ---------------- causal flash attention (MFMA, double-buffered K/V) -------
// block = (bh, 64-row q-tile), 4 waves; wave w owns q rows [qbase+w*16, +16).
// qt-BALANCED grid mapping: CU slot cu = bid&255 gets, across grp = bid>>8,
// qt = {h8, 31-h8, 8+h8, 23-h8} (h8 = cu>>5) — per-CU iteration sum is 66 for
// every CU (was 4..128: (bid+256k)&31 gave identical qt per CU slot).
// Side effect: all 4 co-resident blocks share bh -> K/V L1/L2 reuse.
__global__ __launch_bounds__(256) void attn_kernel(
    const unsigned short* __restrict__ Q, const unsigned short* __restrict__ K,
    const unsigned short* __restrict__ VT, unsigned short* __restrict__ Y) {
  __shared__ unsigned short Ks[2][64 * 64];
  __shared__ unsigned short Vs[2][64 * 64];
  __shared__ unsigned short Ps[4][16 * 64];
  int bid = blockIdx.x;
  int cu = bid & 255, grp = bid >> 8;
  int bh = cu & 31;
  int h8 = cu >> 5;
  int qt = (grp == 0) ? h8 : (grp == 1) ? 31 - h8 : (grp == 2) ? 8 + h8 : 23 - h8;
  int qbase = qt * 64;
  int tid = threadIdx.x, lane = tid & 63, w = tid >> 6;
  int g = lane >> 4, c = lane & 15;
  const unsigned short* Qg = Q + (size_t)bh * Sc * 64;
  const unsigned short* Kg = K + (size_t)bh * Sc * 64;
  const unsigned short* Vg = VT + (size_t)bh * 64 * Sc;
  // Q fragments (A-layout: row=c, k=g*8+j), d-halves 0 / 32
  int q0 = qbase + w * 16;
  bf16x8 qa0 = *(const bf16x8*)(Qg + (size_t)(q0 + c) * 64 + g * 8);
  bf16x8 qa1 = *(const bf16x8*)(Qg + (size_t)(q0 + c) * 64 + 32 + g * 8);
  f32x4 O0 = {0.f, 0.f, 0.f, 0.f}, O1 = O0, O2 = O0, O3 = O0;
  float m[4] = {-1e30f, -1e30f, -1e30f, -1e30f};
  float l[4] = {0.f, 0.f, 0.f, 0.f};
  // staging source precompute: LDS linear slot (r, sl) holds key-block sl^(r&7)
  int r0s = tid >> 3;               // rows 0..31 (call 0)
  int b0s = (tid & 7) ^ (r0s & 7);  // source 16B block
  int r1s = (256 + tid) >> 3;       // rows 32..63 (call 1)
  int b1s = (tid & 7) ^ (r1s & 7);
  size_t kOff0 = (size_t)r0s * 64 + b0s * 8;
  size_t kOff1 = (size_t)r1s * 64 + b1s * 8;
  size_t vOff0 = (size_t)r0s * Sc + b0s * 8;
  size_t vOff1 = (size_t)r1s * Sc + b1s * 8;
  unsigned short* Pw = Ps[w];
  const f32x4 zero = {0.f, 0.f, 0.f, 0.f};
  int swc = c & 7;
  int wOff = w * 512;

#define STAGE(kt_, buf_)                                                       \
  {                                                                            \
    const unsigned short* Kt_ = Kg + (size_t)(kt_) * 64 * 64;                  \
    const unsigned short* Vt_ = Vg + (size_t)(kt_) * 64;                       \
    GLOAD_LDS16(Kt_ + kOff0, &Ks[buf_][wOff]);                                 \
    GLOAD_LDS16(Kt_ + kOff1, &Ks[buf_][2048 + wOff]);                          \
    GLOAD_LDS16(Vt_ + vOff0, &Vs[buf_][wOff]);                                 \
    GLOAD_LDS16(Vt_ + vOff1, &Vs[buf_][2048 + wOff]);                          \
  }

  STAGE(0, 0);  // prologue
  for (int kt = 0; kt <= qt; ++kt) {
    int buf = kt & 1;
    // barrier: (a) drains this wave's outstanding global_load_lds (vmcnt 0)
    // so Ks/Vs[buf] is complete; (b) all waves done reading buf^1 (kt-1).
    __syncthreads();
    if (kt < qt) STAGE(kt + 1, buf ^ 1);  // async prefetch into other buffer
    const unsigned short* Ksb = Ks[buf];
    const unsigned short* Vsb = Vs[buf];
    // ---- scores: S[q=4g+i][key=kb*16+c] via 2 MFMA per key-block
    f32x4 sA[4];
#pragma unroll
    for (int kb = 0; kb < 4; ++kb) {
      int keyr = kb * 16 + c;
      int sw = keyr & 7;
      bf16x8 k0 = *(const bf16x8*)&Ksb[keyr * 64 + ((g ^ sw) << 3)];
      bf16x8 k1 = *(const bf16x8*)&Ksb[keyr * 64 + (((4 + g) ^ sw) << 3)];
      f32x4 a = __builtin_amdgcn_mfma_f32_16x16x32_bf16(qa0, k0, zero, 0, 0, 0);
      a = __builtin_amdgcn_mfma_f32_16x16x32_bf16(qa1, k1, a, 0, 0, 0);
      sA[kb] = a;
    }
    // ---- scale + causal mask + online softmax (rows spread over 16-lane grp)
    float p[4][4], rm[4];
#pragma unroll
    for (int i = 0; i < 4; ++i) rm[i] = -1e30f;
#pragma unroll
    for (int kb = 0; kb < 4; ++kb)
#pragma unroll
      for (int i = 0; i < 4; ++i) {
        float s = sA[kb][i] * 0.125f;
        if (kt == qt && (kb * 16 + c) > (w * 16 + 4 * g + i)) s = -1e30f;
        p[kb][i] = s;
        rm[i] = fmaxf(rm[i], s);
      }
#pragma unroll
    for (int i = 0; i < 4; ++i) {
      rm[i] = fmaxf(rm[i], __shfl_xor(rm[i], 1));
      rm[i] = fmaxf(rm[i], __shfl_xor(rm[i], 2));
      rm[i] = fmaxf(rm[i], __shfl_xor(rm[i], 4));
      rm[i] = fmaxf(rm[i], __shfl_xor(rm[i], 8));
    }
    float sc[4], ls[4];
#pragma unroll
    for (int i = 0; i < 4; ++i) {
      float mn = fmaxf(m[i], rm[i]);
      sc[i] = __expf(m[i] - mn);
      m[i] = mn;
      ls[i] = 0.f;
    }
#pragma unroll
    for (int kb = 0; kb < 4; ++kb)
#pragma unroll
      for (int i = 0; i < 4; ++i) {
        float e = __expf(p[kb][i] - m[i]);
        p[kb][i] = e;
        ls[i] += e;
      }
#pragma unroll
    for (int i = 0; i < 4; ++i) {
      ls[i] += __shfl_xor(ls[i], 1);
      ls[i] += __shfl_xor(ls[i], 2);
      ls[i] += __shfl_xor(ls[i], 4);
      ls[i] += __shfl_xor(ls[i], 8);
      l[i] = l[i] * sc[i] + ls[i];
      O0[i] *= sc[i]; O1[i] *= sc[i]; O2[i] *= sc[i]; O3[i] *= sc[i];
    }
    // ---- P -> wave-private swizzled LDS tile (bf16)
#pragma unroll
    for (int kb = 0; kb < 4; ++kb)
#pragma unroll
      for (int i = 0; i < 4; ++i) {
        int row = 4 * g + i;
        int slot = (kb * 2 + (c >> 3)) ^ (row & 7);
        Pw[row * 64 + slot * 8 + (c & 7)] = f2bf(p[kb][i]);
      }
    // ---- PV: O[q][d] += P(16x64) @ V(64x64) ; A-frag from Pw, B-frag from Vs
    bf16x8 pa0 = *(const bf16x8*)&Pw[c * 64 + ((g ^ swc) << 3)];
    bf16x8 pa1 = *(const bf16x8*)&Pw[c * 64 + (((4 + g) ^ swc) << 3)];
#define PV_DB(db, Ov)                                                          \
    {                                                                          \
      int d_ = db * 16 + c;                                                    \
      bf16x8 v0 = *(const bf16x8*)&Vsb[d_ * 64 + ((g ^ swc) << 3)];            \
      bf16x8 v1 = *(const bf16x8*)&Vsb[d_ * 64 + (((4 + g) ^ swc) << 3)];      \
      Ov = __builtin_amdgcn_mfma_f32_16x16x32_bf16(pa0, v0, Ov, 0, 0, 0);      \
      Ov = __builtin_amdgcn_mfma_f32_16x16x32_bf16(pa1, v1, Ov, 0, 0, 0);      \
    }
    PV_DB(0, O0) PV_DB(1, O1) PV_DB(2, O2) PV_DB(3, O3)
#undef PV_DB
  }
#undef STAGE
  // ---- epilogue: Y[(b, q, h*64+d)] = O/l
  float inv[4];
#pragma unroll
  for (int i = 0; i < 4; ++i) inv[i] = 1.f / l[i];
  int b = bh >> 4, h = bh & 15;
#define WR_DB(db, Ov)                                                          \
  {                                                                            \
    _Pragma("unroll")                                                          \
    for (int i = 0; i < 4; ++i) {                                              \
      int q_ = q0 + 4 * g + i;                                                 \
      Y[(size_t)(b * Sc + q_) * Dc + h * 64 + db * 16 + c] =                   \
          f2bf(Ov[i] * inv[i]);                                                \
    }                                                                          \
  }
  WR_DB(0, O0) WR_DB(1, O1) WR_DB(2, O2) WR_DB(3, O3)
#undef WR_DB
}

// ---------------- launch ----------------
extern "C" void kernel_launch(void* const* d_in, const int* in_sizes, int n_in,
                              void* d_out, int out_size, void* d_ws, size_t ws_size,
                              hipStream_t stream) {
  const float* hidden = (const float*)d_in[0];
  const float* ln1_w = (const float*)d_in[2];
  const float* ln1_b = (const float*)d_in[3];
  const float* q_U = (const float*)d_in[4];
  const float* q_V = (const float*)d_in[5];
  const float* q_b = (const float*)d_in[6];
  const float* k_U = (const float*)d_in[7];
  const float* k_V = (const float*)d_in[8];
  const float* k_b = (const float*)d_in[9];
  const float* v_U = (const float*)d_in[10];
  const float* v_V = (const float*)d_in[11];
  const float* v_b = (const float*)d_in[12];
  const float* out_U = (const float*)d_in[13];
  const float* out_V = (const float*)d_in[14];
  const float* out_b = (const float*)d_in[15];
  const float* ln2_w = (const float*)d_in[16];
  const float* ln2_b = (const float*)d_in[17];
  const float* fc1_U = (const float*)d_in[18];
  const float* fc1_V = (const float*)d_in[19];
  const float* fc1_b = (const float*)d_in[20];
  const float* fc2_U = (const float*)d_in[21];
  const float* fc2_V = (const float*)d_in[22];
  const float* fc2_b = (const float*)d_in[23];
  float* out = (float*)d_out;

  // ---- workspace layout ----
  char* wsb = (char*)d_ws;
  auto US = [&](size_t mb) { return (unsigned short*)(wsb + mb * 1024 * 1024); };
  unsigned short* WqkvT = US(0);    // 1536x1024 bf16  (3MB)
  unsigned short* outUT = US(3);
  unsigned short* outVT = US(4);
  unsigned short* fc1UT = US(5);
  unsigned short* fc1VT = US(6);    // 4096x512 (4MB)
  unsigned short* fc2UT = US(10);   // 512x4096 (4MB)
  unsigned short* fc2VT = US(14);
  unsigned short* xb    = US(15);   // 4096x1024 (8MB)
  unsigned short* Pqkv  = US(23);   // 4096x1536 (12MB) — dead after pv; reused for Vt
  unsigned short* Vt    = US(23);   // (B,H,DH,S) 8MB, overlaps Pqkv (ok: after pv)
  unsigned short* Qb    = US(35);   // (B,H,S,DH) 8MB
  unsigned short* Kb    = US(43);
  unsigned short* Vb    = US(51);
  unsigned short* Yb    = US(59);   // 4096x1024 (8MB)
  unsigned short* Tb    = US(67);   // 4096x512 (4MB)
  float*          hb    = (float*)(wsb + 71ull * 1024 * 1024);  // 16MB
  unsigned short* ab    = US(87);   // 4096x4096 (32MB) -> ends 119MB

  // ---- 1. all 9 weight transposes (f32 -> bf16 N x K) in ONE dispatch ----
  TransArgs ta;
  auto setT = [&](int i, const float* s, unsigned short* d, int R, int C,
                  int& acc) {
    ta.src[i] = s; ta.dst[i] = d; ta.R[i] = R; ta.C[i] = C;
    ta.bstart[i] = acc; acc += (R / 32) * (C / 32);
  };
  int accB = 0;
  setT(0, q_U, WqkvT, 1024, 512, accB);
  setT(1, k_U, WqkvT + 512 * 1024, 1024, 512, accB);
  setT(2, v_U, WqkvT + 1024 * 1024, 1024, 512, accB);
  setT(3, out_U, outUT, 1024, 512, accB);
  setT(4, out_V, outVT, 512, 1024, accB);
  setT(5, fc1_U, fc1UT, 1024, 512, accB);
  setT(6, fc1_V, fc1VT, 512, 4096, accB);
  setT(7, fc2_U, fc2UT, 4096, 512, accB);
  setT(8, fc2_V, fc2VT, 512, 1024, accB);
  ta.bstart[9] = accB;  // 7680
  transpose_cvt_all<<<accB, 256, 0, stream>>>(ta);

  // ---- 2. LN1 -> xb (bf16) ----
  ln_kernel<<<Nt, 256, 0, stream>>>(hidden, ln1_w, ln1_b, xb);
  // ---- 3. batched QKV rank projection ----
  gemm_bf<true, 0, false, false><<<dim3(NP3 / 128, Nt / 128), 256, 0, stream>>>(
      xb, WqkvT, nullptr, nullptr, Pqkv, Nt, NP3, Dc);
  // ---- 4. per-head R->DH (+bias) -> Q,K,V (B,H,S,DH) bf16, one launch ----
  int pvBlocks = Nt * Hc * DHc / 256;
  pv3_kernel<<<dim3(pvBlocks, 3), 256, 0, stream>>>(
      Pqkv, q_V, k_V, v_V, q_b, k_b, v_b, Qb, Kb, Vb);
  // ---- 4b. V -> V^T (B,H,DH,S) (Pqkv region is dead now) ----
  transpose_hd<<<dim3(Sc / 32, 2, Bc * Hc), 256, 0, stream>>>(Vb, Vt);
  // ---- 5. attention -> Yb (B,S,D) bf16 ----
  attn_kernel<<<Bc * Hc * (Sc / 64), 256, 0, stream>>>(Qb, Kb, Vt, Yb);
  // ---- 6. out-proj (N=512 GEMM uses BN=64 grid for full CU coverage) ----
  gemm_bf_n64<true, 0, false, false><<<dim3(512 / 64, Nt / 128), 256, 0, stream>>>(
      Yb, outUT, nullptr, nullptr, Tb, Nt, 512, Dc);
  gemm_bf<false, 0, true, true><<<dim3(Dc / 128, Nt / 128), 256, 0, stream>>>(
      Tb, outVT, out_b, hidden, hb, Nt, Dc, 512);
  // ---- 7. LN2 -> xb (bf16) ----
  ln_kernel<<<Nt, 256, 0, stream>>>(hb, ln2_w, ln2_b, xb);
  // ---- 8. MLP ----
  gemm_bf_n64<true, 0, false, false><<<dim3(512 / 64, Nt / 128), 256, 0, stream>>>(
      xb, fc1UT, nullptr, nullptr, Tb, Nt, 512, Dc);
  gemm_bf<true, 1, true, false><<<dim3(4096 / 128, Nt / 128), 256, 0, stream>>>(
      Tb, fc1VT, fc1_b, nullptr, ab, Nt, 4096, 512);
  gemm_bf_n64<true, 0, false, false><<<dim3(512 / 64, Nt / 128), 256, 0, stream>>>(
      ab, fc2UT, nullptr, nullptr, Tb, Nt, 512, 4096);
  gemm_bf<false, 0, true, true><<<dim3(Dc / 128, Nt / 128), 256, 0, stream>>>(
      Tb, fc2VT, fc2_b, hb, out, Nt, Dc, 512);
}